// Round 7
// baseline (690.572 us; speedup 1.0000x reference)
//
#include <hip/hip_runtime.h>
#include <cstddef>
#include <cstdint>

typedef unsigned short ushort_t;
typedef __attribute__((ext_vector_type(4))) float f32x4;
typedef __attribute__((ext_vector_type(8))) short bf16x8;

#define BB   8192
#define AA   16
#define BA   131072

// ---------------------------------------------------------------------------
// bf16 helpers
// ---------------------------------------------------------------------------
__device__ __forceinline__ float bf2f(ushort_t u) {
    union { float f; uint32_t i; } v; v.i = ((uint32_t)u) << 16; return v.f;
}
__device__ __forceinline__ ushort_t f2bf(float f) {
    union { float f; uint32_t i; } v; v.f = f;
    uint32_t r = v.i + 0x7fffu + ((v.i >> 16) & 1u);
    return (ushort_t)(r >> 16);
}
__device__ __forceinline__ void gload_lds16(const void* g, void* l) {
    __builtin_amdgcn_global_load_lds(
        (const __attribute__((address_space(1))) uint32_t*)g,
        (__attribute__((address_space(3))) uint32_t*)l, 16, 0, 0);
}

// ---------------------------------------------------------------------------
// 8-phase 256x256 MFMA GEMM (round-6-verified main loop; 0 bank conflicts).
// MODE 0: C = epilogue(acc+bias [,relu]) bf16 store.
// MODE 1: (diff GEMM) no C store; iimp_out[b][a] = softmax_a(mean(diff^2)).
// MODE 2: (kvq GEMM) stage C into LDS, run 16-agent attention per b,
//         write applied [M][128] bf16 to C. iimp_in read. bias=pbias.
// See round-6 comments for the schedule proof (stage map, vmcnt counting).
// ---------------------------------------------------------------------------
template<int MODE, bool RELU>
__global__ __launch_bounds__(512)
void gemm8p(const ushort_t* __restrict__ A, int lda,
            const ushort_t* __restrict__ A2, int lda2, int ksplit,
            const ushort_t* __restrict__ Bt,
            const float* __restrict__ bias,
            ushort_t* __restrict__ C, int ldc, int K, int lgx, int rpx,
            const float* __restrict__ Wa, const float* __restrict__ ba,
            const float* __restrict__ iimp_in, float* __restrict__ iimp_out)
{
    __shared__ ushort_t lds[65536];   // 2 bufs x (A 16384 + B 16384) ushorts

    const int tid  = threadIdx.x;
    const int w    = tid >> 6;
    const int lane = tid & 63;
    const int wm   = w >> 2;          // 0..1
    const int wn   = w & 3;           // 0..3
    const int fr   = lane & 15;
    const int fq   = lane >> 4;

    const int bid  = blockIdx.x;
    const int xcd  = bid & 7;
    const int slot = bid >> 3;
    const int x    = slot & ((1 << lgx) - 1);
    const int y    = xcd * rpx + (slot >> lgx);
    const size_t brow = (size_t)y * 256;
    const int    bcol = x * 256;

    const int NT = K >> 6;            // K-tiles (even)
    const int NI = NT >> 1;

    const int srl = tid >> 3;         // 0..63 row-local (staging)
    const int spg = tid & 7;          // phys granule

    f32x4 acc[8][4];
#pragma unroll
    for (int m = 0; m < 8; ++m)
#pragma unroll
        for (int n = 0; n < 4; ++n) acc[m][n] = (f32x4){0.f, 0.f, 0.f, 0.f};

    auto stageA = [&](int T, int s, int bi) {
        const int k0  = T << 6;
        const int row = (srl < 32) ? s * 32 + srl : 128 + s * 32 + (srl - 32);
        const int col = ((spg ^ (row & 7)) << 3);
        const ushort_t* src;
        if (k0 >= ksplit) src = A2 + (brow + row) * (size_t)lda2 + (k0 - ksplit) + col;
        else              src = A  + (brow + row) * (size_t)lda  + k0 + col;
        gload_lds16(src, &lds[(bi << 15) + row * 64 + spg * 8]);
    };
    auto stageB = [&](int T, int c, int bi) {
        const int k0  = T << 6;
        const int row = c * 64 + srl;
        const int col = ((spg ^ (row & 7)) << 3);
        gload_lds16(Bt + (size_t)(bcol + row) * K + k0 + col,
                    &lds[(bi << 15) + 16384 + row * 64 + spg * 8]);
    };

    // prologue: tile0 (4 units), tile1 first 3 units
    stageA(0, 0, 0); stageB(0, 0, 0);
    stageA(0, 1, 0); stageB(0, 1, 0);
    stageA(0, 2, 0); stageB(0, 2, 0);
    stageA(0, 3, 0); stageB(0, 3, 0);
    stageA(1, 0, 1); stageB(1, 0, 1);
    stageA(1, 1, 1); stageB(1, 1, 1);
    stageA(1, 2, 1); stageB(1, 2, 1);

    bf16x8 breg[4][2];

    for (int i = 0; i < NI; ++i) {
        const bool more = (i + 1 < NI);
#pragma unroll
        for (int h = 0; h < 2; ++h) {
            const int bufA = h << 15;
            const int bufB = (h << 15) + 16384;
#pragma unroll
            for (int q = 0; q < 4; ++q) {
                if (q == 0) {
                    if (h == 0 || more) asm volatile("s_waitcnt vmcnt(6)" ::: "memory");
                    else                asm volatile("s_waitcnt vmcnt(0)" ::: "memory");
                    __builtin_amdgcn_sched_barrier(0);
                    __builtin_amdgcn_s_barrier();
#pragma unroll
                    for (int n = 0; n < 4; ++n)
#pragma unroll
                        for (int kk = 0; kk < 2; ++kk) {
                            const int row = wn * 64 + n * 16 + fr;
                            const int gp  = ((kk * 4 + fq) ^ (row & 7)) << 3;
                            breg[n][kk] = *(const bf16x8*)&lds[bufB + row * 64 + gp];
                        }
                }
                bf16x8 areg[2][2];
#pragma unroll
                for (int j = 0; j < 2; ++j)
#pragma unroll
                    for (int kk = 0; kk < 2; ++kk) {
                        const int row = wm * 128 + (2 * q + j) * 16 + fr;
                        const int gp  = ((kk * 4 + fq) ^ (row & 7)) << 3;
                        areg[j][kk] = *(const bf16x8*)&lds[bufA + row * 64 + gp];
                    }
                if (h == 0) {
                    if (q == 0)      { stageA(2*i+1, 3, 1); stageB(2*i+1, 3, 1); }
                    else if (more)   { stageA(2*i+2, q-1, 0); stageB(2*i+2, q-1, 0); }
                } else {
                    if (q == 0) { if (more) { stageA(2*i+2, 3, 0); stageB(2*i+2, 3, 0); } }
                    else        { if (more) { stageA(2*i+3, q-1, 1); stageB(2*i+3, q-1, 1); } }
                }
                __builtin_amdgcn_s_barrier();
                __builtin_amdgcn_s_setprio(1);
#pragma unroll
                for (int j = 0; j < 2; ++j)
#pragma unroll
                    for (int n = 0; n < 4; ++n)
#pragma unroll
                        for (int kk = 0; kk < 2; ++kk)
                            acc[2*q+j][n] = __builtin_amdgcn_mfma_f32_16x16x32_bf16(
                                areg[j][kk], breg[n][kk], acc[2*q+j][n], 0, 0, 0);
                __builtin_amdgcn_s_setprio(0);
                __builtin_amdgcn_s_barrier();
            }
        }
    }
    // all waves past final barrier; all LDS reads consumed -> LDS reusable.

    if (MODE == 0) {
#pragma unroll
        for (int m = 0; m < 8; ++m) {
            const size_t rowb = brow + wm * 128 + m * 16 + fq * 4;
#pragma unroll
            for (int n = 0; n < 4; ++n) {
                const int col = bcol + wn * 64 + n * 16 + fr;
                const float bv = bias[col];
#pragma unroll
                for (int r = 0; r < 4; ++r) {
                    float v = acc[m][n][r] + bv;
                    if (RELU) v = fmaxf(v, 0.f);
                    C[(rowb + r) * (size_t)ldc + col] = f2bf(v);
                }
            }
        }
    }

    if (MODE == 1) {
        // diff row-sumsq -> per-b softmax -> iimp_out. Pad cols give 0.
        float* rowsq = (float*)lds;
        if (tid < 256) rowsq[tid] = 0.f;
        __syncthreads();
#pragma unroll
        for (int m = 0; m < 8; ++m) {
#pragma unroll
            for (int r = 0; r < 4; ++r) {
                float s = 0.f;
#pragma unroll
                for (int n = 0; n < 4; ++n) {
                    const int col = wn * 64 + n * 16 + fr;
                    const float v = acc[m][n][r] + bias[col];
                    s += v * v;
                }
                s += __shfl_xor(s, 1);
                s += __shfl_xor(s, 2);
                s += __shfl_xor(s, 4);
                s += __shfl_xor(s, 8);
                if (fr == 0)
                    atomicAdd(&rowsq[wm * 128 + m * 16 + fq * 4 + r], s);
            }
        }
        __syncthreads();
        if (tid < 16) {
            const int rb = tid * 16;
            float mv[16], mx = -1e30f;
#pragma unroll
            for (int a = 0; a < 16; ++a) {
                mv[a] = rowsq[rb + a] * (1.f / 128.f);
                mx = fmaxf(mx, mv[a]);
            }
            float e[16], den = 0.f;
#pragma unroll
            for (int a = 0; a < 16; ++a) { e[a] = __expf(mv[a] - mx); den += e[a]; }
            const float inv = 1.f / den;
            const size_t b = brow / 16 + tid;
#pragma unroll
            for (int a = 0; a < 16; ++a) iimp_out[b * 16 + a] = e[a] * inv;
        }
    }

    if (MODE == 2) {
        // ---- stage kvq C into LDS bf16 [256][196] -----------------------
        const int KSTR = 196;
        ushort_t* kv    = lds;                               // 50176 ushorts
        float*    kp    = (float*)(lds + 50176);             // 256 f32
        float*    attnw = (float*)(lds + 50176 + 512);       // 4096 f32
#pragma unroll
        for (int m = 0; m < 8; ++m) {
            const int row = wm * 128 + m * 16 + fq * 4;
#pragma unroll
            for (int n = 0; n < 4; ++n) {
                const int col = wn * 64 + n * 16 + fr;
                if (col < 192) {
                    const float bv = bias[col];
#pragma unroll
                    for (int r = 0; r < 4; ++r)
                        kv[(row + r) * KSTR + col] = f2bf(acc[m][n][r] + bv);
                }
            }
        }
        __syncthreads();

        const int b  = tid >> 5;        // 0..15 local b
        const int tl = tid & 31;
        const int rb = b * 16;

        // kpart[j] = flat_key . Wa[32:,j]  (2 halves of 256 summed via shfl)
        {
            const int j = tl & 15, half = tl >> 4;
            float s = 0.f;
            for (int c = half * 256; c < half * 256 + 256; ++c) {
                const int a = c >> 5, cc = c & 31;
                s += bf2f(kv[(rb + a) * KSTR + cc]) * Wa[(32 + c) * 16 + j];
            }
            s += __shfl_down(s, 16);
            if (half == 0) kp[b * 16 + j] = s;
        }
        __syncthreads();

        // logits + softmax + 0.5*iimp : 256 threads, one (b,i) row each
        if (tid < 256) {
            const int b2 = tid >> 4, i = tid & 15, rb2 = b2 * 16;
            float l[16];
#pragma unroll
            for (int j = 0; j < 16; ++j) l[j] = kp[b2 * 16 + j] + ba[j];
            for (int qq = 0; qq < 32; ++qq) {
                const float qv = bf2f(kv[(rb2 + i) * KSTR + 32 + qq]);
#pragma unroll
                for (int j = 0; j < 16; ++j) l[j] += qv * Wa[qq * 16 + j];
            }
            float mx = -1e30f;
#pragma unroll
            for (int j = 0; j < 16; ++j) mx = fmaxf(mx, l[j]);
            float den = 0.f;
#pragma unroll
            for (int j = 0; j < 16; ++j) { l[j] = __expf(l[j] - mx); den += l[j]; }
            const float inv = 1.f / den;
            const size_t gb = brow / 16 + b2;
#pragma unroll
            for (int j = 0; j < 16; ++j)
                attnw[(b2 * 16 + i) * 16 + j] = l[j] * inv + 0.5f * iimp_in[gb * 16 + j];
        }
        __syncthreads();

        // apply: thread (b, tl): row i = tl>>1, col half hc = (tl&1)*64
        {
            const int i  = tl >> 1;
            const int hc = (tl & 1) * 64;
            float aw[16];
#pragma unroll
            for (int j = 0; j < 16; ++j) aw[j] = attnw[(b * 16 + i) * 16 + j];
            const size_t orow = (brow + rb + i) * (size_t)ldc;
            for (int c0 = 0; c0 < 64; c0 += 4) {
                float o0 = 0.f, o1 = 0.f, o2 = 0.f, o3 = 0.f;
#pragma unroll
                for (int j = 0; j < 16; ++j) {
                    const ushort_t* vr = &kv[(rb + j) * KSTR + 64 + hc + c0];
                    const float a0 = aw[j];
                    o0 += a0 * bf2f(vr[0]); o1 += a0 * bf2f(vr[1]);
                    o2 += a0 * bf2f(vr[2]); o3 += a0 * bf2f(vr[3]);
                }
                ushort_t pk[4] = { f2bf(o0), f2bf(o1), f2bf(o2), f2bf(o3) };
                *(uint2*)&C[orow + hc + c0] = *(const uint2*)pk;
            }
        }
    }
}

// ---------------------------------------------------------------------------
// 128x128 MFMA GEMM (proven) for the small-N output head.
// ---------------------------------------------------------------------------
template<bool OBF16, bool RELU>
__global__ __launch_bounds__(256)
void gemm_mfma(const ushort_t* __restrict__ A, int lda,
               const ushort_t* __restrict__ A2, int lda2, int ksplit,
               const ushort_t* __restrict__ Bt,
               const float* __restrict__ bias,
               void* __restrict__ C, int ldc, int N, int K, int lgx)
{
    __shared__ ushort_t As[2][128 * 64];
    __shared__ ushort_t Bs[2][128 * 64];

    const int tid  = threadIdx.x;
    const int w    = tid >> 6;
    const int lane = tid & 63;
    const int wm   = w >> 1;
    const int wn   = w & 1;

    const int bid  = blockIdx.x;
    const int xcd  = bid & 7;
    const int slot = bid >> 3;
    const int x    = slot & ((1 << lgx) - 1);
    const int y    = xcd * 128 + (slot >> lgx);
    const size_t brow = (size_t)y * 128;
    const int    bcol = x * 128;

    const int fr   = lane & 15;
    const int fq   = lane >> 4;
    const int srow = lane >> 3;
    const int scol = (lane & 7) << 3;

    f32x4 acc[4][4];
#pragma unroll
    for (int i = 0; i < 4; ++i)
#pragma unroll
        for (int j = 0; j < 4; ++j) acc[i][j] = (f32x4){0.f, 0.f, 0.f, 0.f};

    const int NT = K >> 6;

    auto stage = [&](int buf, int k0) {
#pragma unroll
        for (int i = 0; i < 4; ++i) {
            const int c = (w << 2) + i;
            const int r = (c << 3) + srow;
            const ushort_t* asrc;
            if (k0 >= ksplit)
                asrc = A2 + (brow + r) * (size_t)lda2 + (k0 - ksplit) + scol;
            else
                asrc = A  + (brow + r) * (size_t)lda  + k0 + scol;
            gload_lds16(asrc, &As[buf][(c << 9) + lane * 8]);
            gload_lds16(Bt + (size_t)(bcol + r) * K + k0 + scol,
                        &Bs[buf][(c << 9) + lane * 8]);
        }
    };

    stage(0, 0);
    __syncthreads();

    for (int t = 0; t < NT; ++t) {
        const int cur = t & 1;
        if (t + 1 < NT) stage(cur ^ 1, (t + 1) << 6);
#pragma unroll
        for (int kk = 0; kk < 2; ++kk) {
            bf16x8 a[4], b[4];
#pragma unroll
            for (int f = 0; f < 4; ++f) {
                a[f] = *(const bf16x8*)&As[cur][(wm * 64 + f * 16 + fr) * 64 + kk * 32 + fq * 8];
                b[f] = *(const bf16x8*)&Bs[cur][(wn * 64 + f * 16 + fr) * 64 + kk * 32 + fq * 8];
            }
#pragma unroll
            for (int fm = 0; fm < 4; ++fm)
#pragma unroll
                for (int fn = 0; fn < 4; ++fn)
                    acc[fm][fn] = __builtin_amdgcn_mfma_f32_16x16x32_bf16(
                        a[fm], b[fn], acc[fm][fn], 0, 0, 0);
        }
        __syncthreads();
    }

#pragma unroll
    for (int fm = 0; fm < 4; ++fm) {
        const size_t rowb = brow + wm * 64 + fm * 16 + fq * 4;
#pragma unroll
        for (int fn = 0; fn < 4; ++fn) {
            const int col = bcol + wn * 64 + fn * 16 + fr;
            if (col < N) {
                const float bv = bias[col];
#pragma unroll
                for (int r = 0; r < 4; ++r) {
                    float v = acc[fm][fn][r] + bv;
                    if (RELU) v = fmaxf(v, 0.f);
                    const size_t idx = (rowb + r) * (size_t)ldc + col;
                    if (OBF16) ((ushort_t*)C)[idx] = f2bf(v);
                    else       ((float*)C)[idx]    = v;
                }
            }
        }
    }
}

// ---------------------------------------------------------------------------
// small prep kernels
// ---------------------------------------------------------------------------
__global__ __launch_bounds__(256)
void transpose_w(const float* __restrict__ W, ushort_t* __restrict__ Wt,
                 int K, int N, int Npad)
{
    int idx = blockIdx.x * 256 + threadIdx.x;
    if (idx >= Npad * K) return;
    int n = idx / K, k = idx - n * K;
    float v = (n < N) ? W[(size_t)k * N + n] : 0.f;
    Wt[idx] = f2bf(v);
}

__global__ __launch_bounds__(256)
void transpose_wk(const float* __restrict__ W, ushort_t* __restrict__ Wt,
                  int Ksrc, int N, int ldk, int kOff, float sign)
{
    int idx = blockIdx.x * 256 + threadIdx.x;
    if (idx >= N * Ksrc) return;
    int n = idx / Ksrc, k = idx - n * Ksrc;
    Wt[(size_t)n * ldk + kOff + k] = f2bf(sign * W[(size_t)k * N + n]);
}

__global__ __launch_bounds__(256)
void conv_f32_bf16(const float* __restrict__ src, ushort_t* __restrict__ dst)
{
    size_t q = (size_t)blockIdx.x * 256 + threadIdx.x;
    float4 v = ((const float4*)src)[q];
    ushort_t* d = dst + q * 4;
    d[0] = f2bf(v.x); d[1] = f2bf(v.y); d[2] = f2bf(v.z); d[3] = f2bf(v.w);
}

__global__ __launch_bounds__(256)
void fill_zero(ushort_t* __restrict__ p, int n)
{
    int i = blockIdx.x * 256 + threadIdx.x;
    if (i < n) p[i] = 0;
}

__global__ void pack_cat2(const float* __restrict__ a, const float* __restrict__ b,
                          float* __restrict__ o)
{
    int j = blockIdx.x * 256 + threadIdx.x;
    if (j < 512) o[j] = a[j];
    else if (j < 1024) o[j] = b[j - 512];
}

__global__ void pack_bias(const float* __restrict__ bk, const float* __restrict__ bq,
                          const float* __restrict__ bv, float* __restrict__ pb)
{
    int j = threadIdx.x;
    float v = 0.f;
    if      (j < 32)  v = bk[j];
    else if (j < 64)  v = bq[j - 32];
    else if (j < 192) v = bv[j - 64];
    pb[j] = v;
}

__global__ void make_cbias(const float* __restrict__ bt2, const float* __restrict__ bp3,
                           float* __restrict__ cb)
{
    int j = threadIdx.x;
    cb[j] = (j < 128) ? (bt2[j] - bp3[j]) : 0.f;
}

// ---------------------------------------------------------------------------
// launch
// ---------------------------------------------------------------------------
extern "C" void kernel_launch(void* const* d_in, const int* in_sizes, int n_in,
                              void* d_out, int out_size, void* d_ws, size_t ws_size,
                              hipStream_t stream)
{
    const float* x      = (const float*)d_in[0];
    const float* hidden = (const float*)d_in[1];
    const float* Wk  = (const float*)d_in[2];
    const float* bk  = (const float*)d_in[3];
    const float* Wv  = (const float*)d_in[4];
    const float* bv  = (const float*)d_in[5];
    const float* Wq  = (const float*)d_in[6];
    const float* bq  = (const float*)d_in[7];
    const float* Wa  = (const float*)d_in[8];
    const float* ba  = (const float*)d_in[9];
    const float* Wt1 = (const float*)d_in[10];
    const float* bt1 = (const float*)d_in[11];
    const float* Wt2 = (const float*)d_in[12];
    const float* bt2 = (const float*)d_in[13];
    const float* Wp1 = (const float*)d_in[14];
    const float* bp1 = (const float*)d_in[15];
    const float* Wp2 = (const float*)d_in[16];
    const float* bp2 = (const float*)d_in[17];
    const float* Wp3 = (const float*)d_in[18];
    const float* bp3 = (const float*)d_in[19];
    const float* Wc  = (const float*)d_in[20];
    const float* bc  = (const float*)d_in[21];
    const float* W2  = (const float*)d_in[22];
    const float* b2  = (const float*)d_in[23];

    float*    out = (float*)d_out;
    ushort_t* ws  = (ushort_t*)d_ws;

    // ---- workspace (ushort elements) ------------------------------------
    ushort_t* xb  = ws;                        // [BA*512] x bf16
    ushort_t* ht2 = xb + (size_t)BA * 512;     // [BA*1024] [h_t | h_p1]
    ushort_t* hp2 = ht2 + (size_t)BA * 1024;   // [BA*512] h_p2
    ushort_t* WT  = hp2 + (size_t)BA * 512;
    // aliases (liveness-ordered)
    ushort_t* hiddenb = hp2;                   // after mse-gemm consumed hp2
    ushort_t* applied = ht2;                   // [BA*128] after ht2 dead
    ushort_t* comb    = ht2 + (size_t)BA * 128;// [BA*256]

    ushort_t* Bg1  = WT;                    // 1024*512  [Wt1^T ; Wp1^T]
    ushort_t* Wp2t = Bg1  + 1024 * 512;     // 512*512
    ushort_t* Dt   = Wp2t + 512 * 512;      // 256*1024  [Wt2^T | -Wp3^T ; 0]
    ushort_t* Wkvq = Dt   + 256 * 1024;     // 256*256   [Wk|Wq|Wv|0]^T
    ushort_t* Wct  = Wkvq + 256 * 256;      // 256*384
    ushort_t* W2t  = Wct  + 256 * 384;      // 128*256
    float* g1bias = (float*)(W2t + 128 * 256);
    float* pbias  = g1bias + 1024;
    float* cbias  = pbias + 256;
    float* iimp   = cbias + 256;            // BB*AA floats

    const dim3 blk(256);
    const int BIG = 1 << 30;

    // ---- weight prep -----------------------------------------------------
    transpose_w<<<1024, blk, 0, stream>>>(Wt1, Bg1,             512, 512, 512);
    transpose_w<<<1024, blk, 0, stream>>>(Wp1, Bg1 + 512 * 512, 512, 512, 512);
    transpose_w<<<1024, blk, 0, stream>>>(Wp2, Wp2t, 512, 512, 512);
    transpose_wk<<<256, blk, 0, stream>>>(Wt2, Dt, 512, 128, 1024, 0,    1.f);
    transpose_wk<<<256, blk, 0, stream>>>(Wp3, Dt, 512, 128, 1024, 512, -1.f);
    fill_zero<<<512, blk, 0, stream>>>(Dt + 128 * 1024, 128 * 1024);
    transpose_w<<<32,  blk, 0, stream>>>(Wk, Wkvq + 0 * 256,   256, 32, 32);
    transpose_w<<<32,  blk, 0, stream>>>(Wq, Wkvq + 32 * 256,  256, 32, 32);
    transpose_w<<<128, blk, 0, stream>>>(Wv, Wkvq + 64 * 256,  256, 128, 128);
    transpose_w<<<64,  blk, 0, stream>>>(Wk, Wkvq + 192 * 256, 256, 0, 64);   // zero pad
    transpose_w<<<384, blk, 0, stream>>>(Wc, Wct, 384, 256, 256);
    transpose_w<<<128, blk, 0, stream>>>(W2, W2t, 256, 64, 128);
    pack_cat2<<<4, 256, 0, stream>>>(bt1, bp1, g1bias);
    pack_bias<<<1, 256, 0, stream>>>(bk, bq, bv, pbias);
    make_cbias<<<1, 256, 0, stream>>>(bt2, bp3, cbias);

    // ---- phase 1: predictors ---------------------------------------------
    conv_f32_bf16<<<65536, blk, 0, stream>>>(x, xb);
    // [h_t | h_p1] = relu(x @ [Wt1|Wp1] + [bt1|bp1])
    gemm8p<0, true><<<2048, 512, 0, stream>>>(
        xb, 512, xb, 512, BIG, Bg1, g1bias, ht2, 1024, 512, 2, 64,
        nullptr, nullptr, nullptr, nullptr);
    // h_p2 = relu(h_p1 @ Wp2 + bp2)
    gemm8p<0, true><<<1024, 512, 0, stream>>>(
        ht2 + 512, 1024, ht2 + 512, 1024, BIG, Wp2t, bp2, hp2, 512, 512, 1, 64,
        nullptr, nullptr, nullptr, nullptr);
    // fused: diff = [h_t|h_p2] @ [Wt2;-Wp3] + cbias -> row sumsq -> softmax -> iimp
    gemm8p<1, false><<<512, 512, 0, stream>>>(
        ht2, 1024, hp2, 512, 512, Dt, cbias, nullptr, 0, 1024, 0, 64,
        nullptr, nullptr, nullptr, iimp);

    // ---- phase 2: communicate (fused kvq GEMM + attention) ----------------
    conv_f32_bf16<<<32768, blk, 0, stream>>>(hidden, hiddenb);
    gemm8p<2, false><<<512, 512, 0, stream>>>(
        hiddenb, 256, hiddenb, 256, BIG, Wkvq, pbias, applied, 128, 256, 0, 64,
        Wa, ba, iimp, nullptr);

    // ---- phase 3: combine + head -----------------------------------------
    // comb = relu([applied|hidden] @ Wc + bc)
    gemm8p<0, true><<<512, 512, 0, stream>>>(
        applied, 128, hiddenb, 256, 128, Wct, bc, comb, 256, 384, 0, 64,
        nullptr, nullptr, nullptr, nullptr);
    // out = comb @ W2 + b2 (f32)
    gemm_mfma<false, false><<<1024, blk, 0, stream>>>(
        comb, 256, comb, 256, BIG, W2t, b2, out, 64, 64, 256, 0);
}

// Round 8
// 633.022 us; speedup vs baseline: 1.0909x; 1.0909x over previous
//
#include <hip/hip_runtime.h>
#include <cstddef>
#include <cstdint>

typedef unsigned short ushort_t;
typedef __attribute__((ext_vector_type(4))) float f32x4;
typedef __attribute__((ext_vector_type(8))) short bf16x8;

#define BB   8192
#define AA   16
#define BA   131072

// ---------------------------------------------------------------------------
// bf16 helpers
// ---------------------------------------------------------------------------
__device__ __forceinline__ float bf2f(ushort_t u) {
    union { float f; uint32_t i; } v; v.i = ((uint32_t)u) << 16; return v.f;
}
__device__ __forceinline__ ushort_t f2bf(float f) {
    union { float f; uint32_t i; } v; v.f = f;
    uint32_t r = v.i + 0x7fffu + ((v.i >> 16) & 1u);
    return (ushort_t)(r >> 16);
}
__device__ __forceinline__ void gload_lds16(const void* g, void* l) {
    __builtin_amdgcn_global_load_lds(
        (const __attribute__((address_space(1))) uint32_t*)g,
        (__attribute__((address_space(3))) uint32_t*)l, 16, 0, 0);
}

// ---------------------------------------------------------------------------
// 8-phase 256x256 MFMA GEMM — EXACT round-6 kernel (195 us on big GEMMs,
// 0 bank conflicts, verified). See round-6 comments for the schedule proof.
// ---------------------------------------------------------------------------
template<bool RELU>
__global__ __launch_bounds__(512, 2)
void gemm8p(const ushort_t* __restrict__ A, int lda,
            const ushort_t* __restrict__ A2, int lda2, int ksplit,
            const ushort_t* __restrict__ Bt,
            const float* __restrict__ bias,
            ushort_t* __restrict__ C, int ldc, int K, int lgx, int rpx)
{
    __shared__ ushort_t lds[65536];   // 2 bufs x (A 16384 + B 16384) ushorts

    const int tid  = threadIdx.x;
    const int w    = tid >> 6;
    const int lane = tid & 63;
    const int wm   = w >> 2;          // 0..1
    const int wn   = w & 3;           // 0..3
    const int fr   = lane & 15;
    const int fq   = lane >> 4;

    const int bid  = blockIdx.x;
    const int xcd  = bid & 7;
    const int slot = bid >> 3;
    const int x    = slot & ((1 << lgx) - 1);
    const int y    = xcd * rpx + (slot >> lgx);
    const size_t brow = (size_t)y * 256;
    const int    bcol = x * 256;

    const int NT = K >> 6;            // K-tiles (even)
    const int NI = NT >> 1;

    const int srl = tid >> 3;         // 0..63 row-local (staging)
    const int spg = tid & 7;          // phys granule

    f32x4 acc[8][4];
#pragma unroll
    for (int m = 0; m < 8; ++m)
#pragma unroll
        for (int n = 0; n < 4; ++n) acc[m][n] = (f32x4){0.f, 0.f, 0.f, 0.f};

    auto stageA = [&](int T, int s, int bi) {
        const int k0  = T << 6;
        const int row = (srl < 32) ? s * 32 + srl : 128 + s * 32 + (srl - 32);
        const int col = ((spg ^ (row & 7)) << 3);
        const ushort_t* src;
        if (k0 >= ksplit) src = A2 + (brow + row) * (size_t)lda2 + (k0 - ksplit) + col;
        else              src = A  + (brow + row) * (size_t)lda  + k0 + col;
        gload_lds16(src, &lds[(bi << 15) + row * 64 + spg * 8]);
    };
    auto stageB = [&](int T, int c, int bi) {
        const int k0  = T << 6;
        const int row = c * 64 + srl;
        const int col = ((spg ^ (row & 7)) << 3);
        gload_lds16(Bt + (size_t)(bcol + row) * K + k0 + col,
                    &lds[(bi << 15) + 16384 + row * 64 + spg * 8]);
    };

    // prologue: tile0 (4 units), tile1 first 3 units
    stageA(0, 0, 0); stageB(0, 0, 0);
    stageA(0, 1, 0); stageB(0, 1, 0);
    stageA(0, 2, 0); stageB(0, 2, 0);
    stageA(0, 3, 0); stageB(0, 3, 0);
    stageA(1, 0, 1); stageB(1, 0, 1);
    stageA(1, 1, 1); stageB(1, 1, 1);
    stageA(1, 2, 1); stageB(1, 2, 1);

    bf16x8 breg[4][2];

    for (int i = 0; i < NI; ++i) {
        const bool more = (i + 1 < NI);
#pragma unroll
        for (int h = 0; h < 2; ++h) {
            const int bufA = h << 15;
            const int bufB = (h << 15) + 16384;
#pragma unroll
            for (int q = 0; q < 4; ++q) {
                if (q == 0) {
                    if (h == 0 || more) asm volatile("s_waitcnt vmcnt(6)" ::: "memory");
                    else                asm volatile("s_waitcnt vmcnt(0)" ::: "memory");
                    __builtin_amdgcn_sched_barrier(0);
                    __builtin_amdgcn_s_barrier();
#pragma unroll
                    for (int n = 0; n < 4; ++n)
#pragma unroll
                        for (int kk = 0; kk < 2; ++kk) {
                            const int row = wn * 64 + n * 16 + fr;
                            const int gp  = ((kk * 4 + fq) ^ (row & 7)) << 3;
                            breg[n][kk] = *(const bf16x8*)&lds[bufB + row * 64 + gp];
                        }
                }
                bf16x8 areg[2][2];
#pragma unroll
                for (int j = 0; j < 2; ++j)
#pragma unroll
                    for (int kk = 0; kk < 2; ++kk) {
                        const int row = wm * 128 + (2 * q + j) * 16 + fr;
                        const int gp  = ((kk * 4 + fq) ^ (row & 7)) << 3;
                        areg[j][kk] = *(const bf16x8*)&lds[bufA + row * 64 + gp];
                    }
                if (h == 0) {
                    if (q == 0)      { stageA(2*i+1, 3, 1); stageB(2*i+1, 3, 1); }
                    else if (more)   { stageA(2*i+2, q-1, 0); stageB(2*i+2, q-1, 0); }
                } else {
                    if (q == 0) { if (more) { stageA(2*i+2, 3, 0); stageB(2*i+2, 3, 0); } }
                    else        { if (more) { stageA(2*i+3, q-1, 1); stageB(2*i+3, q-1, 1); } }
                }
                __builtin_amdgcn_s_barrier();
                __builtin_amdgcn_s_setprio(1);
#pragma unroll
                for (int j = 0; j < 2; ++j)
#pragma unroll
                    for (int n = 0; n < 4; ++n)
#pragma unroll
                        for (int kk = 0; kk < 2; ++kk)
                            acc[2*q+j][n] = __builtin_amdgcn_mfma_f32_16x16x32_bf16(
                                areg[j][kk], breg[n][kk], acc[2*q+j][n], 0, 0, 0);
                __builtin_amdgcn_s_setprio(0);
                __builtin_amdgcn_s_barrier();
            }
        }
    }

    // epilogue: C/D layout col=lane&15, row=(lane>>4)*4+r
#pragma unroll
    for (int m = 0; m < 8; ++m) {
        const size_t rowb = brow + wm * 128 + m * 16 + fq * 4;
#pragma unroll
        for (int n = 0; n < 4; ++n) {
            const int col = bcol + wn * 64 + n * 16 + fr;
            const float bv = bias[col];
#pragma unroll
            for (int r = 0; r < 4; ++r) {
                float v = acc[m][n][r] + bv;
                if (RELU) v = fmaxf(v, 0.f);
                C[(rowb + r) * (size_t)ldc + col] = f2bf(v);
            }
        }
    }
}

// ---------------------------------------------------------------------------
// 128x128 MFMA GEMM (proven). MSE=true: no C store; instead per-row sumsq of
// (acc+bias) -> per-16-row softmax -> iimp_out (requires N=128, bcol==0:
// one block owns all cols of 8 complete b-groups).
// ---------------------------------------------------------------------------
template<bool OBF16, bool RELU, bool MSE>
__global__ __launch_bounds__(256)
void gemm_mfma(const ushort_t* __restrict__ A, int lda,
               const ushort_t* __restrict__ A2, int lda2, int ksplit,
               const ushort_t* __restrict__ Bt,
               const float* __restrict__ bias,
               void* __restrict__ C, int ldc, int N, int K, int lgx,
               float* __restrict__ iimp_out)
{
    __shared__ ushort_t As[2][128 * 64];
    __shared__ ushort_t Bs[2][128 * 64];

    const int tid  = threadIdx.x;
    const int w    = tid >> 6;
    const int lane = tid & 63;
    const int wm   = w >> 1;
    const int wn   = w & 1;

    const int bid  = blockIdx.x;
    const int xcd  = bid & 7;
    const int slot = bid >> 3;
    const int x    = slot & ((1 << lgx) - 1);
    const int y    = xcd * 128 + (slot >> lgx);
    const size_t brow = (size_t)y * 128;
    const int    bcol = x * 128;

    const int fr   = lane & 15;
    const int fq   = lane >> 4;
    const int srow = lane >> 3;
    const int scol = (lane & 7) << 3;

    f32x4 acc[4][4];
#pragma unroll
    for (int i = 0; i < 4; ++i)
#pragma unroll
        for (int j = 0; j < 4; ++j) acc[i][j] = (f32x4){0.f, 0.f, 0.f, 0.f};

    const int NT = K >> 6;

    auto stage = [&](int buf, int k0) {
#pragma unroll
        for (int i = 0; i < 4; ++i) {
            const int c = (w << 2) + i;
            const int r = (c << 3) + srow;
            const ushort_t* asrc;
            if (k0 >= ksplit)
                asrc = A2 + (brow + r) * (size_t)lda2 + (k0 - ksplit) + scol;
            else
                asrc = A  + (brow + r) * (size_t)lda  + k0 + scol;
            gload_lds16(asrc, &As[buf][(c << 9) + lane * 8]);
            gload_lds16(Bt + (size_t)(bcol + r) * K + k0 + scol,
                        &Bs[buf][(c << 9) + lane * 8]);
        }
    };

    stage(0, 0);
    __syncthreads();

    for (int t = 0; t < NT; ++t) {
        const int cur = t & 1;
        if (t + 1 < NT) stage(cur ^ 1, (t + 1) << 6);
#pragma unroll
        for (int kk = 0; kk < 2; ++kk) {
            bf16x8 a[4], b[4];
#pragma unroll
            for (int f = 0; f < 4; ++f) {
                a[f] = *(const bf16x8*)&As[cur][(wm * 64 + f * 16 + fr) * 64 + kk * 32 + fq * 8];
                b[f] = *(const bf16x8*)&Bs[cur][(wn * 64 + f * 16 + fr) * 64 + kk * 32 + fq * 8];
            }
#pragma unroll
            for (int fm = 0; fm < 4; ++fm)
#pragma unroll
                for (int fn = 0; fn < 4; ++fn)
                    acc[fm][fn] = __builtin_amdgcn_mfma_f32_16x16x32_bf16(
                        a[fm], b[fn], acc[fm][fn], 0, 0, 0);
        }
        __syncthreads();
    }

    if (MSE) {
        // rows brow..brow+128 = 8 complete b-groups; all 128 cols in-block.
        float* rowsq = (float*)As;                  // LDS reuse (post-barrier)
        if (tid < 128) rowsq[tid] = 0.f;
        __syncthreads();
#pragma unroll
        for (int fm = 0; fm < 4; ++fm) {
#pragma unroll
            for (int r = 0; r < 4; ++r) {
                float s = 0.f;
#pragma unroll
                for (int fn = 0; fn < 4; ++fn) {
                    const int col = wn * 64 + fn * 16 + fr;
                    const float v = acc[fm][fn][r] + bias[col];
                    s += v * v;
                }
                s += __shfl_xor(s, 1);
                s += __shfl_xor(s, 2);
                s += __shfl_xor(s, 4);
                s += __shfl_xor(s, 8);
                if (fr == 0)
                    atomicAdd(&rowsq[wm * 64 + fm * 16 + fq * 4 + r], s);
            }
        }
        __syncthreads();
        if (tid < 8) {
            const int rb = tid * 16;
            float mv[16], mx = -1e30f;
#pragma unroll
            for (int a = 0; a < 16; ++a) {
                mv[a] = rowsq[rb + a] * (1.f / 128.f);
                mx = fmaxf(mx, mv[a]);
            }
            float e[16], den = 0.f;
#pragma unroll
            for (int a = 0; a < 16; ++a) { e[a] = __expf(mv[a] - mx); den += e[a]; }
            const float inv = 1.f / den;
            const size_t b = brow / 16 + tid;
#pragma unroll
            for (int a = 0; a < 16; ++a) iimp_out[b * 16 + a] = e[a] * inv;
        }
        return;
    }

#pragma unroll
    for (int fm = 0; fm < 4; ++fm) {
        const size_t rowb = brow + wm * 64 + fm * 16 + fq * 4;
#pragma unroll
        for (int fn = 0; fn < 4; ++fn) {
            const int col = bcol + wn * 64 + fn * 16 + fr;
            if (col < N) {
                const float bv = bias[col];
#pragma unroll
                for (int r = 0; r < 4; ++r) {
                    float v = acc[fm][fn][r] + bv;
                    if (RELU) v = fmaxf(v, 0.f);
                    const size_t idx = (rowb + r) * (size_t)ldc + col;
                    if (OBF16) ((ushort_t*)C)[idx] = f2bf(v);
                    else       ((float*)C)[idx]    = v;
                }
            }
        }
    }
}

// ---------------------------------------------------------------------------
// small prep kernels
// ---------------------------------------------------------------------------
__global__ __launch_bounds__(256)
void transpose_w(const float* __restrict__ W, ushort_t* __restrict__ Wt,
                 int K, int N, int Npad)
{
    int idx = blockIdx.x * 256 + threadIdx.x;
    if (idx >= Npad * K) return;
    int n = idx / K, k = idx - n * K;
    float v = (n < N) ? W[(size_t)k * N + n] : 0.f;
    Wt[idx] = f2bf(v);
}

__global__ __launch_bounds__(256)
void transpose_wk(const float* __restrict__ W, ushort_t* __restrict__ Wt,
                  int Ksrc, int N, int ldk, int kOff, float sign)
{
    int idx = blockIdx.x * 256 + threadIdx.x;
    if (idx >= N * Ksrc) return;
    int n = idx / Ksrc, k = idx - n * Ksrc;
    Wt[(size_t)n * ldk + kOff + k] = f2bf(sign * W[(size_t)k * N + n]);
}

__global__ __launch_bounds__(256)
void conv_f32_bf16(const float* __restrict__ src, ushort_t* __restrict__ dst)
{
    size_t q = (size_t)blockIdx.x * 256 + threadIdx.x;
    float4 v = ((const float4*)src)[q];
    ushort_t* d = dst + q * 4;
    d[0] = f2bf(v.x); d[1] = f2bf(v.y); d[2] = f2bf(v.z); d[3] = f2bf(v.w);
}

__global__ void pack_cat2(const float* __restrict__ a, const float* __restrict__ b,
                          float* __restrict__ o)
{
    int j = blockIdx.x * 256 + threadIdx.x;
    if (j < 512) o[j] = a[j];
    else if (j < 1024) o[j] = b[j - 512];
}

__global__ void pack_bias(const float* __restrict__ bk, const float* __restrict__ bq,
                          const float* __restrict__ bv, float* __restrict__ pb)
{
    int j = threadIdx.x;
    float v = 0.f;
    if      (j < 32)  v = bk[j];
    else if (j < 64)  v = bq[j - 32];
    else if (j < 192) v = bv[j - 64];
    pb[j] = v;
}

__global__ void make_cbias(const float* __restrict__ bt2, const float* __restrict__ bp3,
                           float* __restrict__ cb)
{
    int j = threadIdx.x;
    cb[j] = bt2[j] - bp3[j];
}

// ---------------------------------------------------------------------------
// attention: kvq packed [BA][192] = [key(32)|qry(32)|val(128)] per row.
// folds qk@Wa, softmax, +0.5*iimp, apply to V; writes applied [BA][128] bf16.
// ---------------------------------------------------------------------------
__global__ __launch_bounds__(256)
void attn_apply(const ushort_t* __restrict__ kvq, const float* __restrict__ Wa,
                const float* __restrict__ ba, const float* __restrict__ iimp,
                ushort_t* __restrict__ applied)
{
    const int b = blockIdx.x, t = threadIdx.x;
    __shared__ float klds[512], qlds[512];
    __shared__ ushort_t vlds[2048];
    __shared__ float part[16][17];
    __shared__ float kp[16];
    __shared__ float attn[16][17];

    for (int i = t; i < 512; i += 256) {
        int a = i >> 5, c = i & 31;
        const size_t base = ((size_t)b * AA + a) * 192;
        klds[i] = bf2f(kvq[base + c]);
        qlds[i] = bf2f(kvq[base + 32 + c]);
    }
    for (int i = t; i < 2048; i += 256) {
        int j = i >> 7, v = i & 127;
        vlds[i] = kvq[((size_t)b * AA + j) * 192 + 64 + v];
    }
    __syncthreads();

    {
        int j = t & 15, seg = t >> 4;
        float s = 0.f;
        for (int c = seg * 32; c < seg * 32 + 32; ++c)
            s += klds[c] * Wa[(32 + c) * 16 + j];
        part[j][seg] = s;
    }
    __syncthreads();
    if (t < 16) {
        float s = 0.f;
#pragma unroll
        for (int seg = 0; seg < 16; ++seg) s += part[t][seg];
        kp[t] = s;
    }
    __syncthreads();

    {
        int i = t >> 4, j = t & 15;
        float s = 0.f;
#pragma unroll
        for (int q = 0; q < 32; ++q) s += qlds[i * 32 + q] * Wa[q * 16 + j];
        attn[i][j] = s + kp[j] + ba[j];
    }
    __syncthreads();
    if (t < 16) {
        float mx = -1e30f;
#pragma unroll
        for (int j = 0; j < 16; ++j) mx = fmaxf(mx, attn[t][j]);
        float e[16], den = 0.f;
#pragma unroll
        for (int j = 0; j < 16; ++j) { e[j] = __expf(attn[t][j] - mx); den += e[j]; }
        float inv = 1.f / den;
#pragma unroll
        for (int j = 0; j < 16; ++j)
            attn[t][j] = e[j] * inv + 0.5f * iimp[b * 16 + j];
    }
    __syncthreads();

    for (int o = t; o < 2048; o += 256) {
        int i = o >> 7, v = o & 127;
        float s = 0.f;
#pragma unroll
        for (int j = 0; j < 16; ++j) s += attn[i][j] * bf2f(vlds[j * 128 + v]);
        applied[((size_t)b * AA + i) * 128 + v] = f2bf(s);
    }
}

// ---------------------------------------------------------------------------
// launch
// ---------------------------------------------------------------------------
extern "C" void kernel_launch(void* const* d_in, const int* in_sizes, int n_in,
                              void* d_out, int out_size, void* d_ws, size_t ws_size,
                              hipStream_t stream)
{
    const float* x      = (const float*)d_in[0];
    const float* hidden = (const float*)d_in[1];
    const float* Wk  = (const float*)d_in[2];
    const float* bk  = (const float*)d_in[3];
    const float* Wv  = (const float*)d_in[4];
    const float* bv  = (const float*)d_in[5];
    const float* Wq  = (const float*)d_in[6];
    const float* bq  = (const float*)d_in[7];
    const float* Wa  = (const float*)d_in[8];
    const float* ba  = (const float*)d_in[9];
    const float* Wt1 = (const float*)d_in[10];
    const float* bt1 = (const float*)d_in[11];
    const float* Wt2 = (const float*)d_in[12];
    const float* bt2 = (const float*)d_in[13];
    const float* Wp1 = (const float*)d_in[14];
    const float* bp1 = (const float*)d_in[15];
    const float* Wp2 = (const float*)d_in[16];
    const float* bp2 = (const float*)d_in[17];
    const float* Wp3 = (const float*)d_in[18];
    const float* bp3 = (const float*)d_in[19];
    const float* Wc  = (const float*)d_in[20];
    const float* bc  = (const float*)d_in[21];
    const float* W2  = (const float*)d_in[22];
    const float* b2  = (const float*)d_in[23];

    float*    out = (float*)d_out;
    ushort_t* ws  = (ushort_t*)d_ws;

    // ---- workspace (ushort elements) ------------------------------------
    ushort_t* xb  = ws;                        // [BA*512] x bf16
    ushort_t* ht2 = xb + (size_t)BA * 512;     // [BA*1024] [h_t | h_p1]
    ushort_t* hp2 = ht2 + (size_t)BA * 1024;   // [BA*512] h_p2
    ushort_t* WT  = hp2 + (size_t)BA * 512;
    // aliases (liveness-ordered)
    ushort_t* kvq     = xb;                    // [BA*192] (x dead after fused-x)
    ushort_t* hiddenb = hp2;                   // [BA*256] (h_p2 dead after diff)
    ushort_t* applied = ht2;                   // [BA*128] (ht2 dead after diff)
    ushort_t* comb    = ht2 + (size_t)BA * 128;// [BA*256]

    ushort_t* Bg1  = WT;                    // 1024*512  [Wt1^T ; Wp1^T]
    ushort_t* Wp2t = Bg1  + 1024 * 512;     // 512*512
    ushort_t* Dt   = Wp2t + 512 * 512;      // 128*1024  [Wt2^T | -Wp3^T]
    ushort_t* Wkvq = Dt   + 128 * 1024;     // 256*256   [Wk|Wq|Wv|0]^T
    ushort_t* Wct  = Wkvq + 256 * 256;      // 256*384
    ushort_t* W2t  = Wct  + 256 * 384;      // 128*256
    float* g1bias = (float*)(W2t + 128 * 256);
    float* pbias  = g1bias + 1024;
    float* cbias  = pbias + 256;
    float* iimp   = cbias + 128;            // BB*AA floats

    const dim3 blk(256);
    const int BIG = 1 << 30;

    // ---- weight prep -----------------------------------------------------
    transpose_w<<<1024, blk, 0, stream>>>(Wt1, Bg1,             512, 512, 512);
    transpose_w<<<1024, blk, 0, stream>>>(Wp1, Bg1 + 512 * 512, 512, 512, 512);
    transpose_w<<<1024, blk, 0, stream>>>(Wp2, Wp2t, 512, 512, 512);
    transpose_wk<<<256, blk, 0, stream>>>(Wt2, Dt, 512, 128, 1024, 0,    1.f);
    transpose_wk<<<256, blk, 0, stream>>>(Wp3, Dt, 512, 128, 1024, 512, -1.f);
    transpose_w<<<32,  blk, 0, stream>>>(Wk, Wkvq + 0 * 256,   256, 32, 32);
    transpose_w<<<32,  blk, 0, stream>>>(Wq, Wkvq + 32 * 256,  256, 32, 32);
    transpose_w<<<128, blk, 0, stream>>>(Wv, Wkvq + 64 * 256,  256, 128, 128);
    transpose_w<<<64,  blk, 0, stream>>>(Wk, Wkvq + 192 * 256, 256, 0, 64);   // zero pad
    transpose_w<<<384, blk, 0, stream>>>(Wc, Wct, 384, 256, 256);
    transpose_w<<<128, blk, 0, stream>>>(W2, W2t, 256, 64, 128);
    pack_cat2<<<4, 256, 0, stream>>>(bt1, bp1, g1bias);
    pack_bias<<<1, 256, 0, stream>>>(bk, bq, bv, pbias);
    make_cbias<<<1, 128, 0, stream>>>(bt2, bp3, cbias);

    // ---- phase 1: predictors ---------------------------------------------
    conv_f32_bf16<<<65536, blk, 0, stream>>>(x, xb);
    // [h_t | h_p1] = relu(x @ [Wt1|Wp1] + [bt1|bp1])
    gemm8p<true><<<2048, 512, 0, stream>>>(
        xb, 512, xb, 512, BIG, Bg1, g1bias, ht2, 1024, 512, 2, 64);
    // h_p2 = relu(h_p1 @ Wp2 + bp2)
    gemm8p<true><<<1024, 512, 0, stream>>>(
        ht2 + 512, 1024, ht2 + 512, 1024, BIG, Wp2t, bp2, hp2, 512, 512, 1, 64);
    // fused: diff = [h_t|h_p2]@[Wt2;-Wp3]+cbias -> rowsq -> softmax -> iimp
    gemm_mfma<true, false, true><<<1024, blk, 0, stream>>>(
        ht2, 1024, hp2, 512, 512, Dt, cbias, nullptr, 128, 128, 1024, 0, iimp);

    // ---- phase 2: communicate --------------------------------------------
    conv_f32_bf16<<<32768, blk, 0, stream>>>(hidden, hiddenb);
    // kvq = hidden @ [Wk|Wq|Wv] + pbias  (N=192)
    gemm_mfma<true, false, false><<<2048, blk, 0, stream>>>(
        hiddenb, 256, hiddenb, 256, BIG, Wkvq, pbias, kvq, 192, 192, 256, 1, nullptr);
    attn_apply<<<BB, blk, 0, stream>>>(kvq, Wa, ba, iimp, applied);

    // ---- phase 3: combine + head -----------------------------------------
    // comb = relu([applied|hidden] @ Wc + bc)
    gemm8p<true><<<512, 512, 0, stream>>>(
        applied, 128, hiddenb, 256, 128, Wct, bc, comb, 256, 384, 0, 64);
    // out = comb @ W2 + b2 (f32)
    gemm_mfma<false, false, false><<<1024, blk, 0, stream>>>(
        comb, 256, comb, 256, BIG, W2t, b2, out, 64, 64, 256, 0, nullptr);
}

// Round 9
// 616.726 us; speedup vs baseline: 1.1197x; 1.0264x over previous
//
#include <hip/hip_runtime.h>
#include <cstddef>
#include <cstdint>

typedef unsigned short ushort_t;
typedef __attribute__((ext_vector_type(4))) float f32x4;
typedef __attribute__((ext_vector_type(8))) short bf16x8;

#define BB   8192
#define AA   16
#define BA   131072

// ---------------------------------------------------------------------------
// bf16 helpers
// ---------------------------------------------------------------------------
__device__ __forceinline__ float bf2f(ushort_t u) {
    union { float f; uint32_t i; } v; v.i = ((uint32_t)u) << 16; return v.f;
}
__device__ __forceinline__ ushort_t f2bf(float f) {
    union { float f; uint32_t i; } v; v.f = f;
    uint32_t r = v.i + 0x7fffu + ((v.i >> 16) & 1u);
    return (ushort_t)(r >> 16);
}
__device__ __forceinline__ void gload_lds16(const void* g, void* l) {
    __builtin_amdgcn_global_load_lds(
        (const __attribute__((address_space(1))) uint32_t*)g,
        (__attribute__((address_space(3))) uint32_t*)l, 16, 0, 0);
}

// ---------------------------------------------------------------------------
// 8-phase 256x256 MFMA GEMM (round-6-verified main loop; 0 bank conflicts).
// FUSE_OUT=false: C = bf16(relu(acc+bias)), stride ldc.
// FUSE_OUT=true : C is out f32 [M][64]; epilogue stages comb=relu(acc+bias)
//   into LDS (swizzled [256][256] bf16), preloads W2 fragments (Bt2 [64pad][256])
//   to regs, runs in-block 256x64x256 mini-GEMM, writes out = comb@W2^T + b2.
//   Requires ldc-full blocks (bcol==0, lgx==0) so acc holds complete rows.
// ---------------------------------------------------------------------------
template<bool RELU, bool FUSE_OUT>
__global__ __launch_bounds__(512, 2)
void gemm8p(const ushort_t* __restrict__ A, int lda,
            const ushort_t* __restrict__ A2, int lda2, int ksplit,
            const ushort_t* __restrict__ Bt,
            const float* __restrict__ bias,
            ushort_t* __restrict__ C, int ldc, int K, int lgx, int rpx,
            const ushort_t* __restrict__ W2t, const float* __restrict__ b2)
{
    __shared__ ushort_t lds[65536];   // 2 bufs x (A 16384 + B 16384) ushorts

    const int tid  = threadIdx.x;
    const int w    = tid >> 6;
    const int lane = tid & 63;
    const int wm   = w >> 2;          // 0..1
    const int wn   = w & 3;           // 0..3
    const int fr   = lane & 15;
    const int fq   = lane >> 4;

    const int bid  = blockIdx.x;
    const int xcd  = bid & 7;
    const int slot = bid >> 3;
    const int x    = slot & ((1 << lgx) - 1);
    const int y    = xcd * rpx + (slot >> lgx);
    const size_t brow = (size_t)y * 256;
    const int    bcol = x * 256;

    const int NT = K >> 6;            // K-tiles (even)
    const int NI = NT >> 1;

    const int srl = tid >> 3;         // 0..63 row-local (staging)
    const int spg = tid & 7;          // phys granule

    f32x4 acc[8][4];
#pragma unroll
    for (int m = 0; m < 8; ++m)
#pragma unroll
        for (int n = 0; n < 4; ++n) acc[m][n] = (f32x4){0.f, 0.f, 0.f, 0.f};

    auto stageA = [&](int T, int s, int bi) {
        const int k0  = T << 6;
        const int row = (srl < 32) ? s * 32 + srl : 128 + s * 32 + (srl - 32);
        const int col = ((spg ^ (row & 7)) << 3);
        const ushort_t* src;
        if (k0 >= ksplit) src = A2 + (brow + row) * (size_t)lda2 + (k0 - ksplit) + col;
        else              src = A  + (brow + row) * (size_t)lda  + k0 + col;
        gload_lds16(src, &lds[(bi << 15) + row * 64 + spg * 8]);
    };
    auto stageB = [&](int T, int c, int bi) {
        const int k0  = T << 6;
        const int row = c * 64 + srl;
        const int col = ((spg ^ (row & 7)) << 3);
        gload_lds16(Bt + (size_t)(bcol + row) * K + k0 + col,
                    &lds[(bi << 15) + 16384 + row * 64 + spg * 8]);
    };

    // prologue: tile0 (8 units), tile1 first 6 units
    stageA(0, 0, 0); stageB(0, 0, 0);
    stageA(0, 1, 0); stageB(0, 1, 0);
    stageA(0, 2, 0); stageB(0, 2, 0);
    stageA(0, 3, 0); stageB(0, 3, 0);
    stageA(1, 0, 1); stageB(1, 0, 1);
    stageA(1, 1, 1); stageB(1, 1, 1);
    stageA(1, 2, 1); stageB(1, 2, 1);

    bf16x8 breg[4][2];

    for (int i = 0; i < NI; ++i) {
        const bool more = (i + 1 < NI);
#pragma unroll
        for (int h = 0; h < 2; ++h) {
            const int bufA = h << 15;
            const int bufB = (h << 15) + 16384;
#pragma unroll
            for (int q = 0; q < 4; ++q) {
                if (q == 0) {
                    if (h == 0 || more) asm volatile("s_waitcnt vmcnt(6)" ::: "memory");
                    else                asm volatile("s_waitcnt vmcnt(0)" ::: "memory");
                    __builtin_amdgcn_sched_barrier(0);
                    __builtin_amdgcn_s_barrier();
#pragma unroll
                    for (int n = 0; n < 4; ++n)
#pragma unroll
                        for (int kk = 0; kk < 2; ++kk) {
                            const int row = wn * 64 + n * 16 + fr;
                            const int gp  = ((kk * 4 + fq) ^ (row & 7)) << 3;
                            breg[n][kk] = *(const bf16x8*)&lds[bufB + row * 64 + gp];
                        }
                }
                bf16x8 areg[2][2];
#pragma unroll
                for (int j = 0; j < 2; ++j)
#pragma unroll
                    for (int kk = 0; kk < 2; ++kk) {
                        const int row = wm * 128 + (2 * q + j) * 16 + fr;
                        const int gp  = ((kk * 4 + fq) ^ (row & 7)) << 3;
                        areg[j][kk] = *(const bf16x8*)&lds[bufA + row * 64 + gp];
                    }
                if (h == 0) {
                    if (q == 0)      { stageA(2*i+1, 3, 1); stageB(2*i+1, 3, 1); }
                    else if (more)   { stageA(2*i+2, q-1, 0); stageB(2*i+2, q-1, 0); }
                } else {
                    if (q == 0) { if (more) { stageA(2*i+2, 3, 0); stageB(2*i+2, 3, 0); } }
                    else        { if (more) { stageA(2*i+3, q-1, 1); stageB(2*i+3, q-1, 1); } }
                }
                if (q == 0) asm volatile("s_waitcnt lgkmcnt(8)" ::: "memory");
                __builtin_amdgcn_s_barrier();
                __builtin_amdgcn_s_setprio(1);
#pragma unroll
                for (int j = 0; j < 2; ++j)
#pragma unroll
                    for (int n = 0; n < 4; ++n)
#pragma unroll
                        for (int kk = 0; kk < 2; ++kk)
                            acc[2*q+j][n] = __builtin_amdgcn_mfma_f32_16x16x32_bf16(
                                areg[j][kk], breg[n][kk], acc[2*q+j][n], 0, 0, 0);
                __builtin_amdgcn_s_setprio(0);
                __builtin_amdgcn_s_barrier();
            }
        }
    }
    // all waves past final barrier; all LDS reads consumed -> LDS reusable.

    if (!FUSE_OUT) {
        // epilogue: C/D layout col=lane&15, row=(lane>>4)*4+r
#pragma unroll
        for (int m = 0; m < 8; ++m) {
            const size_t rowb = brow + wm * 128 + m * 16 + fq * 4;
#pragma unroll
            for (int n = 0; n < 4; ++n) {
                const int col = bcol + wn * 64 + n * 16 + fr;
                const float bv = bias[col];
#pragma unroll
                for (int r = 0; r < 4; ++r) {
                    float v = acc[m][n][r] + bv;
                    if (RELU) v = fmaxf(v, 0.f);
                    C[(rowb + r) * (size_t)ldc + col] = f2bf(v);
                }
            }
        }
    } else {
        // ---- stage comb = relu(acc+bias) into LDS [256][256] bf16 --------
        // swizzle: granule (col>>3) ^ (row&7) within the 32-granule row.
#pragma unroll
        for (int m = 0; m < 8; ++m) {
            const int row = wm * 128 + m * 16 + fq * 4;
#pragma unroll
            for (int n = 0; n < 4; ++n) {
                const int col = wn * 64 + n * 16 + fr;
                const float bv = bias[col];
#pragma unroll
                for (int r = 0; r < 4; ++r) {
                    const float v = fmaxf(acc[m][n][r] + bv, 0.f);
                    const int rr = row + r;
                    const int g  = (col >> 3) ^ (rr & 7);
                    lds[rr * 256 + g * 8 + (col & 7)] = f2bf(v);
                }
            }
        }
        // preload W2 fragments (L2-resident, 32 KB): frag (n2,kk)
        bf16x8 w2f[4][8];
#pragma unroll
        for (int n2 = 0; n2 < 4; ++n2)
#pragma unroll
            for (int kk = 0; kk < 8; ++kk)
                w2f[n2][kk] = *(const bf16x8*)&W2t[(n2 * 16 + fr) * 256 + kk * 32 + fq * 8];
        __syncthreads();
        // mini-GEMM: out[256x64] = comb @ W2^T + b2 ; wave w owns rows w*32..+31
        f32x4 acc2[2][4];
#pragma unroll
        for (int m2 = 0; m2 < 2; ++m2)
#pragma unroll
            for (int n2 = 0; n2 < 4; ++n2) acc2[m2][n2] = (f32x4){0.f, 0.f, 0.f, 0.f};
#pragma unroll
        for (int kk = 0; kk < 8; ++kk) {
#pragma unroll
            for (int m2 = 0; m2 < 2; ++m2) {
                const int row = w * 32 + m2 * 16 + fr;
                const int g   = (kk * 4 + fq) ^ (row & 7);
                const bf16x8 af = *(const bf16x8*)&lds[row * 256 + g * 8];
#pragma unroll
                for (int n2 = 0; n2 < 4; ++n2)
                    acc2[m2][n2] = __builtin_amdgcn_mfma_f32_16x16x32_bf16(
                        af, w2f[n2][kk], acc2[m2][n2], 0, 0, 0);
            }
        }
        float* outp = (float*)C;
#pragma unroll
        for (int m2 = 0; m2 < 2; ++m2) {
            const size_t rowb = brow + w * 32 + m2 * 16 + fq * 4;
#pragma unroll
            for (int n2 = 0; n2 < 4; ++n2) {
                const int col = n2 * 16 + fr;
                const float bv = b2[col];
#pragma unroll
                for (int r = 0; r < 4; ++r)
                    outp[(rowb + r) * 64 + col] = acc2[m2][n2][r] + bv;
            }
        }
    }
}

// ---------------------------------------------------------------------------
// 128x128 MFMA GEMM (proven). MSE=true: no C store; per-row sumsq of
// (acc+bias) -> per-16-row softmax -> iimp_out (N=128, bcol==0).
// ---------------------------------------------------------------------------
template<bool OBF16, bool RELU, bool MSE>
__global__ __launch_bounds__(256)
void gemm_mfma(const ushort_t* __restrict__ A, int lda,
               const ushort_t* __restrict__ A2, int lda2, int ksplit,
               const ushort_t* __restrict__ Bt,
               const float* __restrict__ bias,
               void* __restrict__ C, int ldc, int N, int K, int lgx,
               float* __restrict__ iimp_out)
{
    __shared__ ushort_t As[2][128 * 64];
    __shared__ ushort_t Bs[2][128 * 64];

    const int tid  = threadIdx.x;
    const int w    = tid >> 6;
    const int lane = tid & 63;
    const int wm   = w >> 1;
    const int wn   = w & 1;

    const int bid  = blockIdx.x;
    const int xcd  = bid & 7;
    const int slot = bid >> 3;
    const int x    = slot & ((1 << lgx) - 1);
    const int y    = xcd * 128 + (slot >> lgx);
    const size_t brow = (size_t)y * 128;
    const int    bcol = x * 128;

    const int fr   = lane & 15;
    const int fq   = lane >> 4;
    const int srow = lane >> 3;
    const int scol = (lane & 7) << 3;

    f32x4 acc[4][4];
#pragma unroll
    for (int i = 0; i < 4; ++i)
#pragma unroll
        for (int j = 0; j < 4; ++j) acc[i][j] = (f32x4){0.f, 0.f, 0.f, 0.f};

    const int NT = K >> 6;

    auto stage = [&](int buf, int k0) {
#pragma unroll
        for (int i = 0; i < 4; ++i) {
            const int c = (w << 2) + i;
            const int r = (c << 3) + srow;
            const ushort_t* asrc;
            if (k0 >= ksplit)
                asrc = A2 + (brow + r) * (size_t)lda2 + (k0 - ksplit) + scol;
            else
                asrc = A  + (brow + r) * (size_t)lda  + k0 + scol;
            gload_lds16(asrc, &As[buf][(c << 9) + lane * 8]);
            gload_lds16(Bt + (size_t)(bcol + r) * K + k0 + scol,
                        &Bs[buf][(c << 9) + lane * 8]);
        }
    };

    stage(0, 0);
    __syncthreads();

    for (int t = 0; t < NT; ++t) {
        const int cur = t & 1;
        if (t + 1 < NT) stage(cur ^ 1, (t + 1) << 6);
#pragma unroll
        for (int kk = 0; kk < 2; ++kk) {
            bf16x8 a[4], b[4];
#pragma unroll
            for (int f = 0; f < 4; ++f) {
                a[f] = *(const bf16x8*)&As[cur][(wm * 64 + f * 16 + fr) * 64 + kk * 32 + fq * 8];
                b[f] = *(const bf16x8*)&Bs[cur][(wn * 64 + f * 16 + fr) * 64 + kk * 32 + fq * 8];
            }
#pragma unroll
            for (int fm = 0; fm < 4; ++fm)
#pragma unroll
                for (int fn = 0; fn < 4; ++fn)
                    acc[fm][fn] = __builtin_amdgcn_mfma_f32_16x16x32_bf16(
                        a[fm], b[fn], acc[fm][fn], 0, 0, 0);
        }
        __syncthreads();
    }

    if (MSE) {
        float* rowsq = (float*)As;
        if (tid < 128) rowsq[tid] = 0.f;
        __syncthreads();
#pragma unroll
        for (int fm = 0; fm < 4; ++fm) {
#pragma unroll
            for (int r = 0; r < 4; ++r) {
                float s = 0.f;
#pragma unroll
                for (int fn = 0; fn < 4; ++fn) {
                    const int col = wn * 64 + fn * 16 + fr;
                    const float v = acc[fm][fn][r] + bias[col];
                    s += v * v;
                }
                s += __shfl_xor(s, 1);
                s += __shfl_xor(s, 2);
                s += __shfl_xor(s, 4);
                s += __shfl_xor(s, 8);
                if (fr == 0)
                    atomicAdd(&rowsq[wm * 64 + fm * 16 + fq * 4 + r], s);
            }
        }
        __syncthreads();
        if (tid < 8) {
            const int rb = tid * 16;
            float mv[16], mx = -1e30f;
#pragma unroll
            for (int a = 0; a < 16; ++a) {
                mv[a] = rowsq[rb + a] * (1.f / 128.f);
                mx = fmaxf(mx, mv[a]);
            }
            float e[16], den = 0.f;
#pragma unroll
            for (int a = 0; a < 16; ++a) { e[a] = __expf(mv[a] - mx); den += e[a]; }
            const float inv = 1.f / den;
            const size_t b = brow / 16 + tid;
#pragma unroll
            for (int a = 0; a < 16; ++a) iimp_out[b * 16 + a] = e[a] * inv;
        }
        return;
    }

#pragma unroll
    for (int fm = 0; fm < 4; ++fm) {
        const size_t rowb = brow + wm * 64 + fm * 16 + fq * 4;
#pragma unroll
        for (int fn = 0; fn < 4; ++fn) {
            const int col = bcol + wn * 64 + fn * 16 + fr;
            if (col < N) {
                const float bv = bias[col];
#pragma unroll
                for (int r = 0; r < 4; ++r) {
                    float v = acc[fm][fn][r] + bv;
                    if (RELU) v = fmaxf(v, 0.f);
                    const size_t idx = (rowb + r) * (size_t)ldc + col;
                    if (OBF16) ((ushort_t*)C)[idx] = f2bf(v);
                    else       ((float*)C)[idx]    = v;
                }
            }
        }
    }
}

// ---------------------------------------------------------------------------
// small prep kernels
// ---------------------------------------------------------------------------
__global__ __launch_bounds__(256)
void transpose_w(const float* __restrict__ W, ushort_t* __restrict__ Wt,
                 int K, int N, int Npad)
{
    int idx = blockIdx.x * 256 + threadIdx.x;
    if (idx >= Npad * K) return;
    int n = idx / K, k = idx - n * K;
    float v = (n < N) ? W[(size_t)k * N + n] : 0.f;
    Wt[idx] = f2bf(v);
}

__global__ __launch_bounds__(256)
void transpose_wk(const float* __restrict__ W, ushort_t* __restrict__ Wt,
                  int Ksrc, int N, int ldk, int kOff, float sign)
{
    int idx = blockIdx.x * 256 + threadIdx.x;
    if (idx >= N * Ksrc) return;
    int n = idx / Ksrc, k = idx - n * Ksrc;
    Wt[(size_t)n * ldk + kOff + k] = f2bf(sign * W[(size_t)k * N + n]);
}

__global__ __launch_bounds__(256)
void conv_f32_bf16(const float* __restrict__ src, ushort_t* __restrict__ dst)
{
    size_t q = (size_t)blockIdx.x * 256 + threadIdx.x;
    float4 v = ((const float4*)src)[q];
    ushort_t* d = dst + q * 4;
    d[0] = f2bf(v.x); d[1] = f2bf(v.y); d[2] = f2bf(v.z); d[3] = f2bf(v.w);
}

__global__ void pack_cat2(const float* __restrict__ a, const float* __restrict__ b,
                          float* __restrict__ o)
{
    int j = blockIdx.x * 256 + threadIdx.x;
    if (j < 512) o[j] = a[j];
    else if (j < 1024) o[j] = b[j - 512];
}

__global__ void pack_bias(const float* __restrict__ bk, const float* __restrict__ bq,
                          const float* __restrict__ bv, float* __restrict__ pb)
{
    int j = threadIdx.x;
    float v = 0.f;
    if      (j < 32)  v = bk[j];
    else if (j < 64)  v = bq[j - 32];
    else if (j < 192) v = bv[j - 64];
    pb[j] = v;
}

__global__ void make_cbias(const float* __restrict__ bt2, const float* __restrict__ bp3,
                           float* __restrict__ cb)
{
    int j = threadIdx.x;
    cb[j] = bt2[j] - bp3[j];
}

// ---------------------------------------------------------------------------
// attention: kvq packed [BA][192] = [key(32)|qry(32)|val(128)] per row.
// ---------------------------------------------------------------------------
__global__ __launch_bounds__(256)
void attn_apply(const ushort_t* __restrict__ kvq, const float* __restrict__ Wa,
                const float* __restrict__ ba, const float* __restrict__ iimp,
                ushort_t* __restrict__ applied)
{
    const int b = blockIdx.x, t = threadIdx.x;
    __shared__ float klds[512], qlds[512];
    __shared__ ushort_t vlds[2048];
    __shared__ float part[16][17];
    __shared__ float kp[16];
    __shared__ float attn[16][17];

    for (int i = t; i < 512; i += 256) {
        int a = i >> 5, c = i & 31;
        const size_t base = ((size_t)b * AA + a) * 192;
        klds[i] = bf2f(kvq[base + c]);
        qlds[i] = bf2f(kvq[base + 32 + c]);
    }
    for (int i = t; i < 2048; i += 256) {
        int j = i >> 7, v = i & 127;
        vlds[i] = kvq[((size_t)b * AA + j) * 192 + 64 + v];
    }
    __syncthreads();

    {
        int j = t & 15, seg = t >> 4;
        float s = 0.f;
        for (int c = seg * 32; c < seg * 32 + 32; ++c)
            s += klds[c] * Wa[(32 + c) * 16 + j];
        part[j][seg] = s;
    }
    __syncthreads();
    if (t < 16) {
        float s = 0.f;
#pragma unroll
        for (int seg = 0; seg < 16; ++seg) s += part[t][seg];
        kp[t] = s;
    }
    __syncthreads();

    {
        int i = t >> 4, j = t & 15;
        float s = 0.f;
#pragma unroll
        for (int q = 0; q < 32; ++q) s += qlds[i * 32 + q] * Wa[q * 16 + j];
        attn[i][j] = s + kp[j] + ba[j];
    }
    __syncthreads();
    if (t < 16) {
        float mx = -1e30f;
#pragma unroll
        for (int j = 0; j < 16; ++j) mx = fmaxf(mx, attn[t][j]);
        float e[16], den = 0.f;
#pragma unroll
        for (int j = 0; j < 16; ++j) { e[j] = __expf(attn[t][j] - mx); den += e[j]; }
        float inv = 1.f / den;
#pragma unroll
        for (int j = 0; j < 16; ++j)
            attn[t][j] = e[j] * inv + 0.5f * iimp[b * 16 + j];
    }
    __syncthreads();

    for (int o = t; o < 2048; o += 256) {
        int i = o >> 7, v = o & 127;
        float s = 0.f;
#pragma unroll
        for (int j = 0; j < 16; ++j) s += attn[i][j] * bf2f(vlds[j * 128 + v]);
        applied[((size_t)b * AA + i) * 128 + v] = f2bf(s);
    }
}

// ---------------------------------------------------------------------------
// launch
// ---------------------------------------------------------------------------
extern "C" void kernel_launch(void* const* d_in, const int* in_sizes, int n_in,
                              void* d_out, int out_size, void* d_ws, size_t ws_size,
                              hipStream_t stream)
{
    const float* x      = (const float*)d_in[0];
    const float* hidden = (const float*)d_in[1];
    const float* Wk  = (const float*)d_in[2];
    const float* bk  = (const float*)d_in[3];
    const float* Wv  = (const float*)d_in[4];
    const float* bv  = (const float*)d_in[5];
    const float* Wq  = (const float*)d_in[6];
    const float* bq  = (const float*)d_in[7];
    const float* Wa  = (const float*)d_in[8];
    const float* ba  = (const float*)d_in[9];
    const float* Wt1 = (const float*)d_in[10];
    const float* bt1 = (const float*)d_in[11];
    const float* Wt2 = (const float*)d_in[12];
    const float* bt2 = (const float*)d_in[13];
    const float* Wp1 = (const float*)d_in[14];
    const float* bp1 = (const float*)d_in[15];
    const float* Wp2 = (const float*)d_in[16];
    const float* bp2 = (const float*)d_in[17];
    const float* Wp3 = (const float*)d_in[18];
    const float* bp3 = (const float*)d_in[19];
    const float* Wc  = (const float*)d_in[20];
    const float* bc  = (const float*)d_in[21];
    const float* W2  = (const float*)d_in[22];
    const float* b2  = (const float*)d_in[23];

    float*    out = (float*)d_out;
    ushort_t* ws  = (ushort_t*)d_ws;

    // ---- workspace (ushort elements) ------------------------------------
    ushort_t* xb  = ws;                        // [BA*512] x bf16
    ushort_t* ht2 = xb + (size_t)BA * 512;     // [BA*1024] [h_t | h_p1]
    ushort_t* hp2 = ht2 + (size_t)BA * 1024;   // [BA*512] h_p2
    ushort_t* WT  = hp2 + (size_t)BA * 512;
    // aliases (liveness-ordered)
    ushort_t* kvq     = xb;                    // [BA*192] (x dead after fused-x)
    ushort_t* hiddenb = hp2;                   // [BA*256] (h_p2 dead after diff)
    ushort_t* applied = ht2;                   // [BA*128] (ht2 dead after diff)

    ushort_t* Bg1  = WT;                    // 1024*512  [Wt1^T ; Wp1^T]
    ushort_t* Wp2t = Bg1  + 1024 * 512;     // 512*512
    ushort_t* Dt   = Wp2t + 512 * 512;      // 128*1024  [Wt2^T | -Wp3^T]
    ushort_t* Wkvq = Dt   + 128 * 1024;     // 256*256   [Wk|Wq|Wv|0]^T
    ushort_t* Wct  = Wkvq + 256 * 256;      // 256*384
    ushort_t* W2t  = Wct  + 256 * 384;      // 128*256
    float* g1bias = (float*)(W2t + 128 * 256);
    float* pbias  = g1bias + 1024;
    float* cbias  = pbias + 256;
    float* iimp   = cbias + 128;            // BB*AA floats

    const dim3 blk(256);
    const int BIG = 1 << 30;

    // ---- weight prep -----------------------------------------------------
    transpose_w<<<1024, blk, 0, stream>>>(Wt1, Bg1,             512, 512, 512);
    transpose_w<<<1024, blk, 0, stream>>>(Wp1, Bg1 + 512 * 512, 512, 512, 512);
    transpose_w<<<1024, blk, 0, stream>>>(Wp2, Wp2t, 512, 512, 512);
    transpose_wk<<<256, blk, 0, stream>>>(Wt2, Dt, 512, 128, 1024, 0,    1.f);
    transpose_wk<<<256, blk, 0, stream>>>(Wp3, Dt, 512, 128, 1024, 512, -1.f);
    transpose_w<<<32,  blk, 0, stream>>>(Wk, Wkvq + 0 * 256,   256, 32, 32);
    transpose_w<<<32,  blk, 0, stream>>>(Wq, Wkvq + 32 * 256,  256, 32, 32);
    transpose_w<<<128, blk, 0, stream>>>(Wv, Wkvq + 64 * 256,  256, 128, 128);
    transpose_w<<<64,  blk, 0, stream>>>(Wk, Wkvq + 192 * 256, 256, 0, 64);   // zero pad
    transpose_w<<<384, blk, 0, stream>>>(Wc, Wct, 384, 256, 256);
    transpose_w<<<128, blk, 0, stream>>>(W2, W2t, 256, 64, 128);
    pack_cat2<<<4, 256, 0, stream>>>(bt1, bp1, g1bias);
    pack_bias<<<1, 256, 0, stream>>>(bk, bq, bv, pbias);
    make_cbias<<<1, 128, 0, stream>>>(bt2, bp3, cbias);

    // ---- phase 1: predictors ---------------------------------------------
    conv_f32_bf16<<<65536, blk, 0, stream>>>(x, xb);
    // [h_t | h_p1] = relu(x @ [Wt1|Wp1] + [bt1|bp1])
    gemm8p<true, false><<<2048, 512, 0, stream>>>(
        xb, 512, xb, 512, BIG, Bg1, g1bias, ht2, 1024, 512, 2, 64, nullptr, nullptr);
    // h_p2 = relu(h_p1 @ Wp2 + bp2)
    gemm8p<true, false><<<1024, 512, 0, stream>>>(
        ht2 + 512, 1024, ht2 + 512, 1024, BIG, Wp2t, bp2, hp2, 512, 512, 1, 64, nullptr, nullptr);
    // fused: diff = [h_t|h_p2]@[Wt2;-Wp3]+cbias -> rowsq -> softmax -> iimp
    gemm_mfma<true, false, true><<<1024, blk, 0, stream>>>(
        ht2, 1024, hp2, 512, 512, Dt, cbias, nullptr, 128, 128, 1024, 0, iimp);

    // ---- phase 2: communicate --------------------------------------------
    conv_f32_bf16<<<32768, blk, 0, stream>>>(hidden, hiddenb);
    // kvq = hidden @ [Wk|Wq|Wv] + pbias  (N=192)
    gemm_mfma<true, false, false><<<2048, blk, 0, stream>>>(
        hiddenb, 256, hiddenb, 256, BIG, Wkvq, pbias, kvq, 192, 192, 256, 1, nullptr);
    attn_apply<<<BB, blk, 0, stream>>>(kvq, Wa, ba, iimp, applied);

    // ---- phase 3: combine + output head (fully fused) ---------------------
    // comb = relu([applied|hidden] @ Wc + bc) ; out = comb @ W2 + b2
    gemm8p<true, true><<<512, 512, 0, stream>>>(
        applied, 128, hiddenb, 256, 128, Wct, bc, (ushort_t*)out, 64, 384, 0, 64, W2t, b2);
}

// Round 10
// 599.732 us; speedup vs baseline: 1.1515x; 1.0283x over previous
//
#include <hip/hip_runtime.h>
#include <cstddef>
#include <cstdint>

typedef unsigned short ushort_t;
typedef __attribute__((ext_vector_type(4))) float f32x4;
typedef __attribute__((ext_vector_type(8))) short bf16x8;

#define BB   8192
#define AA   16
#define BA   131072

// ---------------------------------------------------------------------------
// bf16 helpers
// ---------------------------------------------------------------------------
__device__ __forceinline__ float bf2f(ushort_t u) {
    union { float f; uint32_t i; } v; v.i = ((uint32_t)u) << 16; return v.f;
}
__device__ __forceinline__ ushort_t f2bf(float f) {
    union { float f; uint32_t i; } v; v.f = f;
    uint32_t r = v.i + 0x7fffu + ((v.i >> 16) & 1u);
    return (ushort_t)(r >> 16);
}
__device__ __forceinline__ void gload_lds16(const void* g, void* l) {
    __builtin_amdgcn_global_load_lds(
        (const __attribute__((address_space(1))) uint32_t*)g,
        (__attribute__((address_space(3))) uint32_t*)l, 16, 0, 0);
}

// ---------------------------------------------------------------------------
// 8-phase 256x256 MFMA GEMM. Round-10 change vs round-9 (which refcheck'd):
//  (a) mid-phase barrier REMOVED -> one end-barrier per phase. Waves stagger
//      within a phase so LDS-reads of one wave overlap MFMA of another
//      (round-9 was pipe-additive: 620 MFMA + 580 LDS + 410 VALU cyc/phase).
//      Race-safety: every stage at phase g targets regions whose readers all
//      passed end-bar(g-1) (A-strip s read only at phase s; B chunks read
//      only at q0; cross-buf targets disjoint) - unchanged from round-6 proof.
//  (b) staging base pointers precomputed per thread (12 bases); per stage =
//      one pointer add instead of 64-bit mul chain.
// FUSE_OUT as round 9 (combine+output-head fusion).
// ---------------------------------------------------------------------------
template<bool RELU, bool FUSE_OUT>
__global__ __launch_bounds__(512, 2)
void gemm8p(const ushort_t* __restrict__ A, int lda,
            const ushort_t* __restrict__ A2, int lda2, int ksplit,
            const ushort_t* __restrict__ Bt,
            const float* __restrict__ bias,
            ushort_t* __restrict__ C, int ldc, int K, int lgx, int rpx,
            const ushort_t* __restrict__ W2t, const float* __restrict__ b2)
{
    __shared__ ushort_t lds[65536];   // 2 bufs x (A 16384 + B 16384) ushorts

    const int tid  = threadIdx.x;
    const int w    = tid >> 6;
    const int lane = tid & 63;
    const int wm   = w >> 2;          // 0..1
    const int wn   = w & 3;           // 0..3
    const int fr   = lane & 15;
    const int fq   = lane >> 4;

    const int bid  = blockIdx.x;
    const int xcd  = bid & 7;
    const int slot = bid >> 3;
    const int x    = slot & ((1 << lgx) - 1);
    const int y    = xcd * rpx + (slot >> lgx);
    const size_t brow = (size_t)y * 256;
    const int    bcol = x * 256;

    const int NT = K >> 6;            // K-tiles (even)
    const int NI = NT >> 1;

    const int srl = tid >> 3;         // 0..63 row-local (staging)
    const int spg = tid & 7;          // phys granule

    f32x4 acc[8][4];
#pragma unroll
    for (int m = 0; m < 8; ++m)
#pragma unroll
        for (int n = 0; n < 4; ++n) acc[m][n] = (f32x4){0.f, 0.f, 0.f, 0.f};

    // ---- precomputed staging bases (per thread, per strip/chunk) ---------
    const ushort_t* aB1[4];
    const ushort_t* aB2[4];
    const ushort_t* bB[4];
    int ldsA[4], ldsB[4];
#pragma unroll
    for (int s = 0; s < 4; ++s) {
        const int rowA = (srl < 32) ? s * 32 + srl : 128 + s * 32 + (srl - 32);
        const int colA = ((spg ^ (rowA & 7)) << 3);
        aB1[s] = A  + (brow + rowA) * (size_t)lda  + colA;
        aB2[s] = A2 + (brow + rowA) * (size_t)lda2 + colA - ksplit;
        ldsA[s] = rowA * 64 + spg * 8;
        const int rowB = s * 64 + srl;
        const int colB = ((spg ^ (rowB & 7)) << 3);
        bB[s]   = Bt + (size_t)(bcol + rowB) * K + colB;
        ldsB[s] = 16384 + rowB * 64 + spg * 8;
    }

    auto stageA = [&](int T, int s, int bi) {
        const int k0 = T << 6;
        const ushort_t* src = (k0 >= ksplit ? aB2[s] : aB1[s]) + k0;
        gload_lds16(src, &lds[(bi << 15) + ldsA[s]]);
    };
    auto stageB = [&](int T, int c, int bi) {
        gload_lds16(bB[c] + (T << 6), &lds[(bi << 15) + ldsB[c]]);
    };

    // prologue: tile0 (4 units), tile1 first 3 units
    stageA(0, 0, 0); stageB(0, 0, 0);
    stageA(0, 1, 0); stageB(0, 1, 0);
    stageA(0, 2, 0); stageB(0, 2, 0);
    stageA(0, 3, 0); stageB(0, 3, 0);
    stageA(1, 0, 1); stageB(1, 0, 1);
    stageA(1, 1, 1); stageB(1, 1, 1);
    stageA(1, 2, 1); stageB(1, 2, 1);

    bf16x8 breg[4][2];

    for (int i = 0; i < NI; ++i) {
        const bool more = (i + 1 < NI);
#pragma unroll
        for (int h = 0; h < 2; ++h) {
            const int bufA = h << 15;
            const int bufB = (h << 15) + 16384;
#pragma unroll
            for (int q = 0; q < 4; ++q) {
                if (q == 0) {
                    if (h == 0 || more) asm volatile("s_waitcnt vmcnt(6)" ::: "memory");
                    else                asm volatile("s_waitcnt vmcnt(0)" ::: "memory");
                    __builtin_amdgcn_sched_barrier(0);
                    __builtin_amdgcn_s_barrier();
#pragma unroll
                    for (int n = 0; n < 4; ++n)
#pragma unroll
                        for (int kk = 0; kk < 2; ++kk) {
                            const int row = wn * 64 + n * 16 + fr;
                            const int gp  = ((kk * 4 + fq) ^ (row & 7)) << 3;
                            breg[n][kk] = *(const bf16x8*)&lds[bufB + row * 64 + gp];
                        }
                }
                bf16x8 areg[2][2];
#pragma unroll
                for (int j = 0; j < 2; ++j)
#pragma unroll
                    for (int kk = 0; kk < 2; ++kk) {
                        const int row = wm * 128 + (2 * q + j) * 16 + fr;
                        const int gp  = ((kk * 4 + fq) ^ (row & 7)) << 3;
                        areg[j][kk] = *(const bf16x8*)&lds[bufA + row * 64 + gp];
                    }
                if (h == 0) {
                    if (q == 0)      { stageA(2*i+1, 3, 1); stageB(2*i+1, 3, 1); }
                    else if (more)   { stageA(2*i+2, q-1, 0); stageB(2*i+2, q-1, 0); }
                } else {
                    if (q == 0) { if (more) { stageA(2*i+2, 3, 0); stageB(2*i+2, 3, 0); } }
                    else        { if (more) { stageA(2*i+3, q-1, 1); stageB(2*i+3, q-1, 1); } }
                }
                // (mid barrier removed: waves stagger; end barrier bounds it)
                __builtin_amdgcn_s_setprio(1);
#pragma unroll
                for (int j = 0; j < 2; ++j)
#pragma unroll
                    for (int n = 0; n < 4; ++n)
#pragma unroll
                        for (int kk = 0; kk < 2; ++kk)
                            acc[2*q+j][n] = __builtin_amdgcn_mfma_f32_16x16x32_bf16(
                                areg[j][kk], breg[n][kk], acc[2*q+j][n], 0, 0, 0);
                __builtin_amdgcn_s_setprio(0);
                __builtin_amdgcn_s_barrier();
            }
        }
    }
    // all waves past final barrier; all LDS reads consumed -> LDS reusable.

    if (!FUSE_OUT) {
        // epilogue: C/D layout col=lane&15, row=(lane>>4)*4+r
#pragma unroll
        for (int m = 0; m < 8; ++m) {
            const size_t rowb = brow + wm * 128 + m * 16 + fq * 4;
#pragma unroll
            for (int n = 0; n < 4; ++n) {
                const int col = bcol + wn * 64 + n * 16 + fr;
                const float bv = bias[col];
#pragma unroll
                for (int r = 0; r < 4; ++r) {
                    float v = acc[m][n][r] + bv;
                    if (RELU) v = fmaxf(v, 0.f);
                    C[(rowb + r) * (size_t)ldc + col] = f2bf(v);
                }
            }
        }
    } else {
        // ---- stage comb = relu(acc+bias) into LDS [256][256] bf16 --------
#pragma unroll
        for (int m = 0; m < 8; ++m) {
            const int row = wm * 128 + m * 16 + fq * 4;
#pragma unroll
            for (int n = 0; n < 4; ++n) {
                const int col = wn * 64 + n * 16 + fr;
                const float bv = bias[col];
#pragma unroll
                for (int r = 0; r < 4; ++r) {
                    const float v = fmaxf(acc[m][n][r] + bv, 0.f);
                    const int rr = row + r;
                    const int g  = (col >> 3) ^ (rr & 7);
                    lds[rr * 256 + g * 8 + (col & 7)] = f2bf(v);
                }
            }
        }
        // preload W2 fragments (L2-resident, 32 KB): frag (n2,kk)
        bf16x8 w2f[4][8];
#pragma unroll
        for (int n2 = 0; n2 < 4; ++n2)
#pragma unroll
            for (int kk = 0; kk < 8; ++kk)
                w2f[n2][kk] = *(const bf16x8*)&W2t[(n2 * 16 + fr) * 256 + kk * 32 + fq * 8];
        __syncthreads();
        // mini-GEMM: out[256x64] = comb @ W2^T + b2 ; wave w owns rows w*32..+31
        f32x4 acc2[2][4];
#pragma unroll
        for (int m2 = 0; m2 < 2; ++m2)
#pragma unroll
            for (int n2 = 0; n2 < 4; ++n2) acc2[m2][n2] = (f32x4){0.f, 0.f, 0.f, 0.f};
#pragma unroll
        for (int kk = 0; kk < 8; ++kk) {
#pragma unroll
            for (int m2 = 0; m2 < 2; ++m2) {
                const int row = w * 32 + m2 * 16 + fr;
                const int g   = (kk * 4 + fq) ^ (row & 7);
                const bf16x8 af = *(const bf16x8*)&lds[row * 256 + g * 8];
#pragma unroll
                for (int n2 = 0; n2 < 4; ++n2)
                    acc2[m2][n2] = __builtin_amdgcn_mfma_f32_16x16x32_bf16(
                        af, w2f[n2][kk], acc2[m2][n2], 0, 0, 0);
            }
        }
        float* outp = (float*)C;
#pragma unroll
        for (int m2 = 0; m2 < 2; ++m2) {
            const size_t rowb = brow + w * 32 + m2 * 16 + fq * 4;
#pragma unroll
            for (int n2 = 0; n2 < 4; ++n2) {
                const int col = n2 * 16 + fr;
                const float bv = b2[col];
#pragma unroll
                for (int r = 0; r < 4; ++r)
                    outp[(rowb + r) * 64 + col] = acc2[m2][n2][r] + bv;
            }
        }
    }
}

// ---------------------------------------------------------------------------
// 128x128 MFMA GEMM (proven). MSE=true: no C store; per-row sumsq of
// (acc+bias) -> per-16-row softmax -> iimp_out (N=128, bcol==0).
// ---------------------------------------------------------------------------
template<bool OBF16, bool RELU, bool MSE>
__global__ __launch_bounds__(256)
void gemm_mfma(const ushort_t* __restrict__ A, int lda,
               const ushort_t* __restrict__ A2, int lda2, int ksplit,
               const ushort_t* __restrict__ Bt,
               const float* __restrict__ bias,
               void* __restrict__ C, int ldc, int N, int K, int lgx,
               float* __restrict__ iimp_out)
{
    __shared__ ushort_t As[2][128 * 64];
    __shared__ ushort_t Bs[2][128 * 64];

    const int tid  = threadIdx.x;
    const int w    = tid >> 6;
    const int lane = tid & 63;
    const int wm   = w >> 1;
    const int wn   = w & 1;

    const int bid  = blockIdx.x;
    const int xcd  = bid & 7;
    const int slot = bid >> 3;
    const int x    = slot & ((1 << lgx) - 1);
    const int y    = xcd * 128 + (slot >> lgx);
    const size_t brow = (size_t)y * 128;
    const int    bcol = x * 128;

    const int fr   = lane & 15;
    const int fq   = lane >> 4;
    const int srow = lane >> 3;
    const int scol = (lane & 7) << 3;

    f32x4 acc[4][4];
#pragma unroll
    for (int i = 0; i < 4; ++i)
#pragma unroll
        for (int j = 0; j < 4; ++j) acc[i][j] = (f32x4){0.f, 0.f, 0.f, 0.f};

    const int NT = K >> 6;

    auto stage = [&](int buf, int k0) {
#pragma unroll
        for (int i = 0; i < 4; ++i) {
            const int c = (w << 2) + i;
            const int r = (c << 3) + srow;
            const ushort_t* asrc;
            if (k0 >= ksplit)
                asrc = A2 + (brow + r) * (size_t)lda2 + (k0 - ksplit) + scol;
            else
                asrc = A  + (brow + r) * (size_t)lda  + k0 + scol;
            gload_lds16(asrc, &As[buf][(c << 9) + lane * 8]);
            gload_lds16(Bt + (size_t)(bcol + r) * K + k0 + scol,
                        &Bs[buf][(c << 9) + lane * 8]);
        }
    };

    stage(0, 0);
    __syncthreads();

    for (int t = 0; t < NT; ++t) {
        const int cur = t & 1;
        if (t + 1 < NT) stage(cur ^ 1, (t + 1) << 6);
#pragma unroll
        for (int kk = 0; kk < 2; ++kk) {
            bf16x8 a[4], b[4];
#pragma unroll
            for (int f = 0; f < 4; ++f) {
                a[f] = *(const bf16x8*)&As[cur][(wm * 64 + f * 16 + fr) * 64 + kk * 32 + fq * 8];
                b[f] = *(const bf16x8*)&Bs[cur][(wn * 64 + f * 16 + fr) * 64 + kk * 32 + fq * 8];
            }
#pragma unroll
            for (int fm = 0; fm < 4; ++fm)
#pragma unroll
                for (int fn = 0; fn < 4; ++fn)
                    acc[fm][fn] = __builtin_amdgcn_mfma_f32_16x16x32_bf16(
                        a[fm], b[fn], acc[fm][fn], 0, 0, 0);
        }
        __syncthreads();
    }

    if (MSE) {
        float* rowsq = (float*)As;
        if (tid < 128) rowsq[tid] = 0.f;
        __syncthreads();
#pragma unroll
        for (int fm = 0; fm < 4; ++fm) {
#pragma unroll
            for (int r = 0; r < 4; ++r) {
                float s = 0.f;
#pragma unroll
                for (int fn = 0; fn < 4; ++fn) {
                    const int col = wn * 64 + fn * 16 + fr;
                    const float v = acc[fm][fn][r] + bias[col];
                    s += v * v;
                }
                s += __shfl_xor(s, 1);
                s += __shfl_xor(s, 2);
                s += __shfl_xor(s, 4);
                s += __shfl_xor(s, 8);
                if (fr == 0)
                    atomicAdd(&rowsq[wm * 64 + fm * 16 + fq * 4 + r], s);
            }
        }
        __syncthreads();
        if (tid < 8) {
            const int rb = tid * 16;
            float mv[16], mx = -1e30f;
#pragma unroll
            for (int a = 0; a < 16; ++a) {
                mv[a] = rowsq[rb + a] * (1.f / 128.f);
                mx = fmaxf(mx, mv[a]);
            }
            float e[16], den = 0.f;
#pragma unroll
            for (int a = 0; a < 16; ++a) { e[a] = __expf(mv[a] - mx); den += e[a]; }
            const float inv = 1.f / den;
            const size_t b = brow / 16 + tid;
#pragma unroll
            for (int a = 0; a < 16; ++a) iimp_out[b * 16 + a] = e[a] * inv;
        }
        return;
    }

#pragma unroll
    for (int fm = 0; fm < 4; ++fm) {
        const size_t rowb = brow + wm * 64 + fm * 16 + fq * 4;
#pragma unroll
        for (int fn = 0; fn < 4; ++fn) {
            const int col = bcol + wn * 64 + fn * 16 + fr;
            if (col < N) {
                const float bv = bias[col];
#pragma unroll
                for (int r = 0; r < 4; ++r) {
                    float v = acc[fm][fn][r] + bv;
                    if (RELU) v = fmaxf(v, 0.f);
                    const size_t idx = (rowb + r) * (size_t)ldc + col;
                    if (OBF16) ((ushort_t*)C)[idx] = f2bf(v);
                    else       ((float*)C)[idx]    = v;
                }
            }
        }
    }
}

// ---------------------------------------------------------------------------
// small prep kernels
// ---------------------------------------------------------------------------
__global__ __launch_bounds__(256)
void transpose_w(const float* __restrict__ W, ushort_t* __restrict__ Wt,
                 int K, int N, int Npad)
{
    int idx = blockIdx.x * 256 + threadIdx.x;
    if (idx >= Npad * K) return;
    int n = idx / K, k = idx - n * K;
    float v = (n < N) ? W[(size_t)k * N + n] : 0.f;
    Wt[idx] = f2bf(v);
}

__global__ __launch_bounds__(256)
void transpose_wk(const float* __restrict__ W, ushort_t* __restrict__ Wt,
                  int Ksrc, int N, int ldk, int kOff, float sign)
{
    int idx = blockIdx.x * 256 + threadIdx.x;
    if (idx >= N * Ksrc) return;
    int n = idx / Ksrc, k = idx - n * Ksrc;
    Wt[(size_t)n * ldk + kOff + k] = f2bf(sign * W[(size_t)k * N + n]);
}

__global__ __launch_bounds__(256)
void conv_f32_bf16(const float* __restrict__ src, ushort_t* __restrict__ dst)
{
    size_t q = (size_t)blockIdx.x * 256 + threadIdx.x;
    float4 v = ((const float4*)src)[q];
    ushort_t* d = dst + q * 4;
    d[0] = f2bf(v.x); d[1] = f2bf(v.y); d[2] = f2bf(v.z); d[3] = f2bf(v.w);
}

__global__ void pack_cat2(const float* __restrict__ a, const float* __restrict__ b,
                          float* __restrict__ o)
{
    int j = blockIdx.x * 256 + threadIdx.x;
    if (j < 512) o[j] = a[j];
    else if (j < 1024) o[j] = b[j - 512];
}

__global__ void pack_bias(const float* __restrict__ bk, const float* __restrict__ bq,
                          const float* __restrict__ bv, float* __restrict__ pb)
{
    int j = threadIdx.x;
    float v = 0.f;
    if      (j < 32)  v = bk[j];
    else if (j < 64)  v = bq[j - 32];
    else if (j < 192) v = bv[j - 64];
    pb[j] = v;
}

__global__ void make_cbias(const float* __restrict__ bt2, const float* __restrict__ bp3,
                           float* __restrict__ cb)
{
    int j = threadIdx.x;
    cb[j] = bt2[j] - bp3[j];
}

// ---------------------------------------------------------------------------
// attention: kvq packed [BA][192] = [key(32)|qry(32)|val(128)] per row.
// ---------------------------------------------------------------------------
__global__ __launch_bounds__(256)
void attn_apply(const ushort_t* __restrict__ kvq, const float* __restrict__ Wa,
                const float* __restrict__ ba, const float* __restrict__ iimp,
                ushort_t* __restrict__ applied)
{
    const int b = blockIdx.x, t = threadIdx.x;
    __shared__ float klds[512], qlds[512];
    __shared__ ushort_t vlds[2048];
    __shared__ float part[16][17];
    __shared__ float kp[16];
    __shared__ float attn[16][17];

    for (int i = t; i < 512; i += 256) {
        int a = i >> 5, c = i & 31;
        const size_t base = ((size_t)b * AA + a) * 192;
        klds[i] = bf2f(kvq[base + c]);
        qlds[i] = bf2f(kvq[base + 32 + c]);
    }
    for (int i = t; i < 2048; i += 256) {
        int j = i >> 7, v = i & 127;
        vlds[i] = kvq[((size_t)b * AA + j) * 192 + 64 + v];
    }
    __syncthreads();

    {
        int j = t & 15, seg = t >> 4;
        float s = 0.f;
        for (int c = seg * 32; c < seg * 32 + 32; ++c)
            s += klds[c] * Wa[(32 + c) * 16 + j];
        part[j][seg] = s;
    }
    __syncthreads();
    if (t < 16) {
        float s = 0.f;
#pragma unroll
        for (int seg = 0; seg < 16; ++seg) s += part[t][seg];
        kp[t] = s;
    }
    __syncthreads();

    {
        int i = t >> 4, j = t & 15;
        float s = 0.f;
#pragma unroll
        for (int q = 0; q < 32; ++q) s += qlds[i * 32 + q] * Wa[q * 16 + j];
        attn[i][j] = s + kp[j] + ba[j];
    }
    __syncthreads();
    if (t < 16) {
        float mx = -1e30f;
#pragma unroll
        for (int j = 0; j < 16; ++j) mx = fmaxf(mx, attn[t][j]);
        float e[16], den = 0.f;
#pragma unroll
        for (int j = 0; j < 16; ++j) { e[j] = __expf(attn[t][j] - mx); den += e[j]; }
        float inv = 1.f / den;
#pragma unroll
        for (int j = 0; j < 16; ++j)
            attn[t][j] = e[j] * inv + 0.5f * iimp[b * 16 + j];
    }
    __syncthreads();

    for (int o = t; o < 2048; o += 256) {
        int i = o >> 7, v = o & 127;
        float s = 0.f;
#pragma unroll
        for (int j = 0; j < 16; ++j) s += attn[i][j] * bf2f(vlds[j * 128 + v]);
        applied[((size_t)b * AA + i) * 128 + v] = f2bf(s);
    }
}

// ---------------------------------------------------------------------------
// launch
// ---------------------------------------------------------------------------
extern "C" void kernel_launch(void* const* d_in, const int* in_sizes, int n_in,
                              void* d_out, int out_size, void* d_ws, size_t ws_size,
                              hipStream_t stream)
{
    const float* x      = (const float*)d_in[0];
    const float* hidden = (const float*)d_in[1];
    const float* Wk  = (const float*)d_in[2];
    const float* bk  = (const float*)d_in[3];
    const float* Wv  = (const float*)d_in[4];
    const float* bv  = (const float*)d_in[5];
    const float* Wq  = (const float*)d_in[6];
    const float* bq  = (const float*)d_in[7];
    const float* Wa  = (const float*)d_in[8];
    const float* ba  = (const float*)d_in[9];
    const float* Wt1 = (const float*)d_in[10];
    const float* bt1 = (const float*)d_in[11];
    const float* Wt2 = (const float*)d_in[12];
    const float* bt2 = (const float*)d_in[13];
    const float* Wp1 = (const float*)d_in[14];
    const float* bp1 = (const float*)d_in[15];
    const float* Wp2 = (const float*)d_in[16];
    const float* bp2 = (const float*)d_in[17];
    const float* Wp3 = (const float*)d_in[18];
    const float* bp3 = (const float*)d_in[19];
    const float* Wc  = (const float*)d_in[20];
    const float* bc  = (const float*)d_in[21];
    const float* W2  = (const float*)d_in[22];
    const float* b2  = (const float*)d_in[23];

    float*    out = (float*)d_out;
    ushort_t* ws  = (ushort_t*)d_ws;

    // ---- workspace (ushort elements) ------------------------------------
    ushort_t* xb  = ws;                        // [BA*512] x bf16
    ushort_t* ht2 = xb + (size_t)BA * 512;     // [BA*1024] [h_t | h_p1]
    ushort_t* hp2 = ht2 + (size_t)BA * 1024;   // [BA*512] h_p2
    ushort_t* WT  = hp2 + (size_t)BA * 512;
    // aliases (liveness-ordered)
    ushort_t* kvq     = xb;                    // [BA*192] (x dead after fused-x)
    ushort_t* hiddenb = hp2;                   // [BA*256] (h_p2 dead after diff)
    ushort_t* applied = ht2;                   // [BA*128] (ht2 dead after diff)

    ushort_t* Bg1  = WT;                    // 1024*512  [Wt1^T ; Wp1^T]
    ushort_t* Wp2t = Bg1  + 1024 * 512;     // 512*512
    ushort_t* Dt   = Wp2t + 512 * 512;      // 128*1024  [Wt2^T | -Wp3^T]
    ushort_t* Wkvq = Dt   + 128 * 1024;     // 256*256   [Wk|Wq|Wv|0]^T
    ushort_t* Wct  = Wkvq + 256 * 256;      // 256*384
    ushort_t* W2t  = Wct  + 256 * 384;      // 128*256
    float* g1bias = (float*)(W2t + 128 * 256);
    float* pbias  = g1bias + 1024;
    float* cbias  = pbias + 256;
    float* iimp   = cbias + 128;            // BB*AA floats

    const dim3 blk(256);
    const int BIG = 1 << 30;

    // ---- weight prep -----------------------------------------------------
    transpose_w<<<1024, blk, 0, stream>>>(Wt1, Bg1,             512, 512, 512);
    transpose_w<<<1024, blk, 0, stream>>>(Wp1, Bg1 + 512 * 512, 512, 512, 512);
    transpose_w<<<1024, blk, 0, stream>>>(Wp2, Wp2t, 512, 512, 512);
    transpose_wk<<<256, blk, 0, stream>>>(Wt2, Dt, 512, 128, 1024, 0,    1.f);
    transpose_wk<<<256, blk, 0, stream>>>(Wp3, Dt, 512, 128, 1024, 512, -1.f);
    transpose_w<<<32,  blk, 0, stream>>>(Wk, Wkvq + 0 * 256,   256, 32, 32);
    transpose_w<<<32,  blk, 0, stream>>>(Wq, Wkvq + 32 * 256,  256, 32, 32);
    transpose_w<<<128, blk, 0, stream>>>(Wv, Wkvq + 64 * 256,  256, 128, 128);
    transpose_w<<<64,  blk, 0, stream>>>(Wk, Wkvq + 192 * 256, 256, 0, 64);   // zero pad
    transpose_w<<<384, blk, 0, stream>>>(Wc, Wct, 384, 256, 256);
    transpose_w<<<128, blk, 0, stream>>>(W2, W2t, 256, 64, 128);
    pack_cat2<<<4, 256, 0, stream>>>(bt1, bp1, g1bias);
    pack_bias<<<1, 256, 0, stream>>>(bk, bq, bv, pbias);
    make_cbias<<<1, 128, 0, stream>>>(bt2, bp3, cbias);

    // ---- phase 1: predictors ---------------------------------------------
    conv_f32_bf16<<<65536, blk, 0, stream>>>(x, xb);
    // [h_t | h_p1] = relu(x @ [Wt1|Wp1] + [bt1|bp1])
    gemm8p<true, false><<<2048, 512, 0, stream>>>(
        xb, 512, xb, 512, BIG, Bg1, g1bias, ht2, 1024, 512, 2, 64, nullptr, nullptr);
    // h_p2 = relu(h_p1 @ Wp2 + bp2)
    gemm8p<true, false><<<1024, 512, 0, stream>>>(
        ht2 + 512, 1024, ht2 + 512, 1024, BIG, Wp2t, bp2, hp2, 512, 512, 1, 64, nullptr, nullptr);
    // fused: diff = [h_t|h_p2]@[Wt2;-Wp3]+cbias -> rowsq -> softmax -> iimp
    gemm_mfma<true, false, true><<<1024, blk, 0, stream>>>(
        ht2, 1024, hp2, 512, 512, Dt, cbias, nullptr, 128, 128, 1024, 0, iimp);

    // ---- phase 2: communicate --------------------------------------------
    conv_f32_bf16<<<32768, blk, 0, stream>>>(hidden, hiddenb);
    // kvq = hidden @ [Wk|Wq|Wv] + pbias  (N=192)
    gemm_mfma<true, false, false><<<2048, blk, 0, stream>>>(
        hiddenb, 256, hiddenb, 256, BIG, Wkvq, pbias, kvq, 192, 192, 256, 1, nullptr);
    attn_apply<<<BB, blk, 0, stream>>>(kvq, Wa, ba, iimp, applied);

    // ---- phase 3: combine + output head (fully fused) ---------------------
    // comb = relu([applied|hidden] @ Wc + bc) ; out = comb @ W2 + b2
    gemm8p<true, true><<<512, 512, 0, stream>>>(
        applied, 128, hiddenb, 256, 128, Wct, bc, (ushort_t*)out, 64, 384, 0, 64, W2t, b2);
}